// Round 5
// baseline (9361.387 us; speedup 1.0000x reference)
//
#include <hip/hip_runtime.h>
#include <hip/hip_bf16.h>

#define N_NODES 100000
#define N_EDGES 800000
#define N_ETOT  900000
#define HEADS   10
#define FXD     78
#define HDIM    780
#define NG      512
#define SEQ     1000
#define CCAP    28032   // chunk row capacity (mean 25000, +22 sigma)
#define GPC     128     // graphs per chunk
#define NCHUNK  4

using bf16 = __hip_bfloat16;

__device__ __forceinline__ float ldv(const float* p){ return *p; }
__device__ __forceinline__ float ldv(const bf16* p){ return __bfloat162float(*p); }
__device__ __forceinline__ void stv(float* p, float v){ *p = v; }
__device__ __forceinline__ void stv(bf16* p, float v){ *p = __float2bfloat16(v); }

__global__ void zero32(int* a, int n){ int i = blockIdx.x*256+threadIdx.x; if(i<n) a[i]=0; }

// ---------------- generic f32 GEMM (small FCs): C = act(A@B [+bias][*sc+sh]) ----------------
template<bool HAS_BIAS, bool HAS_BN, bool RELU>
__global__ __launch_bounds__(256) void gemm_t(
    const float* __restrict__ A, const float* __restrict__ B,
    const float* __restrict__ bias, const float* __restrict__ scale,
    const float* __restrict__ shift, float* __restrict__ C,
    int M, int N, int K, int lda, int ldb, int ldc)
{
    __shared__ float As[16][128 + 4];
    __shared__ float Bs[16][64 + 4];
    const int tid = threadIdx.x;
    const int bm0 = blockIdx.x * 128, bn0 = blockIdx.y * 64;
    const int tr = tid >> 4, tc = tid & 15;
    const int a_k = tid & 15, a_r = tid >> 4;
    const int b_c = tid & 63, b_k = tid >> 6;
    float acc[8][4];
#pragma unroll
    for (int i = 0; i < 8; i++)
#pragma unroll
        for (int j = 0; j < 4; j++) acc[i][j] = 0.f;
    for (int k0 = 0; k0 < K; k0 += 16) {
#pragma unroll
        for (int i = 0; i < 8; i++) {
            int r = bm0 + a_r + i * 16;
            float v = 0.f;
            if (r < M && (k0 + a_k) < K) v = A[(size_t)r * lda + k0 + a_k];
            As[a_k][a_r + i * 16] = v;
        }
#pragma unroll
        for (int i = 0; i < 4; i++) {
            int kk = b_k + i * 4, col = bn0 + b_c;
            float v = 0.f;
            if ((k0 + kk) < K && col < N) v = B[(size_t)(k0 + kk) * ldb + col];
            Bs[kk][b_c] = v;
        }
        __syncthreads();
#pragma unroll
        for (int kk = 0; kk < 16; kk++) {
            float4 a0 = *(const float4*)&As[kk][tr * 8];
            float4 a1 = *(const float4*)&As[kk][tr * 8 + 4];
            float4 b0 = *(const float4*)&Bs[kk][tc * 4];
            float av[8] = {a0.x,a0.y,a0.z,a0.w,a1.x,a1.y,a1.z,a1.w};
            float bv[4] = {b0.x,b0.y,b0.z,b0.w};
#pragma unroll
            for (int i = 0; i < 8; i++)
#pragma unroll
                for (int j = 0; j < 4; j++) acc[i][j] = fmaf(av[i], bv[j], acc[i][j]);
        }
        __syncthreads();
    }
#pragma unroll
    for (int i = 0; i < 8; i++) {
        int r = bm0 + tr * 8 + i;
        if (r >= M) continue;
#pragma unroll
        for (int j = 0; j < 4; j++) {
            int c = bn0 + tc * 4 + j;
            if (c >= N) continue;
            float v = acc[i][j];
            if (HAS_BIAS) v += bias[c];
            if (HAS_BN)   v = v * scale[c] + shift[c];
            if (RELU)     v = fmaxf(v, 0.f);
            C[(size_t)r * ldc + c] = v;
        }
    }
}

// ---------------- prep ----------------
__global__ void prep_att(const float* __restrict__ gw, const float* __restrict__ asrc,
                         const float* __restrict__ adst, float* Asv, float* Adv)
{
    int i = blockIdx.x * 256 + threadIdx.x;
    if (i >= FXD * HEADS) return;
    int f = i / HEADS, hd = i % HEADS;
    float s = 0.f, d = 0.f;
    for (int k = 0; k < FXD; k++) {
        float w = gw[f * HDIM + hd * FXD + k];
        s = fmaf(w, asrc[hd * FXD + k], s);
        d = fmaf(w, adst[hd * FXD + k], d);
    }
    Asv[hd * FXD + f] = s;
    Adv[hd * FXD + f] = d;
}

template<int CI, int CO>
__global__ void transpose_w(const float* __restrict__ w, float* __restrict__ wk)
{
    int i = blockIdx.x * 256 + threadIdx.x;
    if (i >= CI * CO * 16) return;
    int k = i & 15, ci = (i >> 4) % CI, co = i / (16 * CI);
    wk[(k * CI + ci) * CO + co] = w[i];
}

__global__ void prep_bn(const float* bc, const float* g, const float* bb,
                        const float* m, const float* v, float* sc, float* sh, int C, int mode)
{
    int i = blockIdx.x * 256 + threadIdx.x;
    if (i >= C) return;
    float inv = rsqrtf(v[i] + 1e-5f);
    float s = g[i] * inv;
    sc[i] = s;
    sh[i] = (mode == 0) ? (bc[i] - m[i]) * s + bb[i] : (bb[i] - m[i] * s);
}

// ---------------- CSR ----------------
__global__ void hist_deg(const int* __restrict__ ei, int* __restrict__ deg_i)
{
    int e = blockIdx.x * 256 + threadIdx.x;
    if (e >= N_ETOT) return;
    int dst = (e < N_EDGES) ? ei[N_EDGES + e] : e - N_EDGES;
    atomicAdd(&deg_i[dst], 1);
}

__global__ void scan1(const int* __restrict__ in, int* __restrict__ out, int* __restrict__ bsum, int n)
{
    __shared__ int s[256];
    int t = threadIdx.x, i = blockIdx.x * 256 + t;
    int v = (i < n) ? in[i] : 0;
    s[t] = v; __syncthreads();
    for (int off = 1; off < 256; off <<= 1) {
        int u = (t >= off) ? s[t - off] : 0;
        __syncthreads(); s[t] += u; __syncthreads();
    }
    if (i < n) out[i] = s[t] - v;
    if (t == 255) bsum[blockIdx.x] = s[255];
}

__global__ void scan2(int* __restrict__ bsum, int* __restrict__ total, int nb)
{
    if (threadIdx.x == 0 && blockIdx.x == 0) {
        int run = 0;
        for (int b = 0; b < nb; b++) { int t = bsum[b]; bsum[b] = run; run += t; }
        *total = run;
    }
}

__global__ void scan3(int* __restrict__ rs, const int* __restrict__ bsum, int n)
{
    int i = blockIdx.x * 256 + threadIdx.x;
    if (i < n) rs[i] += bsum[i >> 8];
}

__global__ void scatter_csr(const int* __restrict__ ei, const int* __restrict__ rs,
                            int* __restrict__ cursor, int* __restrict__ csr_src)
{
    int e = blockIdx.x * 256 + threadIdx.x;
    if (e >= N_ETOT) return;
    int src, dst;
    if (e < N_EDGES) { src = ei[e]; dst = ei[N_EDGES + e]; }
    else             { src = dst = e - N_EDGES; }
    int ofs = atomicAdd(&cursor[dst], 1);
    csr_src[rs[dst] + ofs] = src;
}

__global__ void gbounds(const int* __restrict__ batch, int* __restrict__ gb)
{
    int g = blockIdx.x * 256 + threadIdx.x;
    if (g > NG) return;
    int lo = 0, hi = N_NODES;
    while (lo < hi) { int mid = (lo + hi) >> 1; if (batch[mid] < g) lo = mid + 1; else hi = mid; }
    gb[g] = lo;
}

__global__ void dinv_k(const int* __restrict__ rs, float* __restrict__ dinv, int n)
{
    int i = blockIdx.x * 256 + threadIdx.x;
    if (i < n) dinv[i] = rsqrtf((float)(rs[i + 1] - rs[i]));
}

// ---------------- GAT ----------------
__global__ void att_scores(const float* __restrict__ x, const float* __restrict__ Asv,
                           const float* __restrict__ Adv, float* as_o, float* ad_o, int N)
{
    int n = blockIdx.x * 256 + threadIdx.x;
    if (n >= N) return;
    float xr[FXD];
#pragma unroll
    for (int k = 0; k < FXD; k++) xr[k] = x[n * FXD + k];
#pragma unroll
    for (int hd = 0; hd < HEADS; hd++) {
        float s = 0.f, d = 0.f;
#pragma unroll
        for (int k = 0; k < FXD; k++) {
            s = fmaf(xr[k], Asv[hd * FXD + k], s);
            d = fmaf(xr[k], Adv[hd * FXD + k], d);
        }
        as_o[n * HEADS + hd] = s;
        ad_o[n * HEADS + hd] = d;
    }
}

// wave per dst: fused softmax (lanes 0..9 hold per-head stats) + aggregation of x
// xagg[dst, hd*78+k] = sum_e alpha[e,hd] * x[src_e, k]
template<typename ST>
__global__ __launch_bounds__(256) void gat_fused(
    const int* __restrict__ rs, const int* __restrict__ csrc,
    const float* __restrict__ as_, const float* __restrict__ ad_,
    const float* __restrict__ x, ST* __restrict__ xagg)
{
    int wid = (blockIdx.x * 256 + threadIdx.x) >> 6;
    int lane = threadIdx.x & 63;
    if (wid >= N_NODES) return;
    int p0 = rs[wid], p1 = rs[wid + 1];
    float m = -1e30f, z = 0.f, ad = 0.f, zinv = 0.f;
    if (lane < HEADS) {
        ad = ad_[wid * HEADS + lane];
        for (int pos = p0; pos < p1; ++pos) {
            float v = as_[csrc[pos] * HEADS + lane] + ad;
            v = v >= 0.f ? v : 0.2f * v;
            m = fmaxf(m, v);
        }
        for (int pos = p0; pos < p1; ++pos) {
            float v = as_[csrc[pos] * HEADS + lane] + ad;
            v = v >= 0.f ? v : 0.2f * v;
            z += __expf(v - m);
        }
        zinv = 1.f / z;
    }
    int hdj[13], kj[13];
#pragma unroll
    for (int j = 0; j < 13; j++) {
        int f = lane + 64 * j;
        hdj[j] = (f < HDIM) ? f / FXD : 0;
        kj[j]  = (f < HDIM) ? f % FXD : 0;
    }
    float acc[13];
#pragma unroll
    for (int j = 0; j < 13; j++) acc[j] = 0.f;
    for (int pos = p0; pos < p1; ++pos) {
        int src = csrc[pos];
        float sc = 0.f;
        if (lane < HEADS) {
            float v = as_[src * HEADS + lane] + ad;
            v = v >= 0.f ? v : 0.2f * v;
            sc = __expf(v - m) * zinv;
        }
        const float* xs = x + (size_t)src * FXD;
#pragma unroll
        for (int j = 0; j < 13; j++) {
            float a = __shfl(sc, hdj[j]);
            int f = lane + 64 * j;
            if (f < HDIM) acc[j] = fmaf(a, xs[kj[j]], acc[j]);
        }
    }
    ST* od = xagg + (size_t)wid * HDIM;
#pragma unroll
    for (int j = 0; j < 13; j++) {
        int f = lane + 64 * j;
        if (f < HDIM) stv(&od[f], acc[j]);
    }
}

// in-place per-head transform: h[r, hd*78+f] = relu(sum_k h[r, hd*78+k]*W[k, hd*78+f] + b)
// block (64 rows, 1 head) reads exactly the region it writes; stage in LDS first -> safe.
template<typename ST>
__global__ __launch_bounds__(256) void gat_headgemm(
    ST* __restrict__ h, const float* __restrict__ W, const float* __restrict__ bias)
{
    __shared__ float As[64][80];
    __shared__ float Bs[FXD][80];
    const int bm0 = blockIdx.x * 64;
    const int hd = blockIdx.y;
    const int tid = threadIdx.x;
    for (int idx = tid; idx < FXD * FXD; idx += 256) {
        int k = idx / FXD, f = idx % FXD;
        Bs[k][f] = W[k * HDIM + hd * FXD + f];
    }
    for (int idx = tid; idx < 64 * FXD; idx += 256) {
        int rl = idx / FXD, c = idx % FXD;
        int r = bm0 + rl;
        As[rl][c] = (r < N_NODES) ? ldv(&h[(size_t)r * HDIM + hd * FXD + c]) : 0.f;
    }
    __syncthreads();
    const int rl = tid >> 2, cg = tid & 3;
    float acc[20];
#pragma unroll
    for (int j = 0; j < 20; j++) acc[j] = 0.f;
    for (int k = 0; k < FXD; k++) {
        float a = As[rl][k];
#pragma unroll
        for (int j = 0; j < 20; j++) {
            int c = cg + 4 * j;
            if (c < FXD) acc[j] = fmaf(a, Bs[k][c], acc[j]);
        }
    }
    int r = bm0 + rl;
    if (r < N_NODES) {
#pragma unroll
        for (int j = 0; j < 20; j++) {
            int c = cg + 4 * j;
            if (c < FXD)
                stv(&h[(size_t)r * HDIM + hd * FXD + c],
                    fmaxf(acc[j] + bias[hd * FXD + c], 0.f));
        }
    }
}

// ---------------- GCN chunked ----------------
template<typename ST>
__global__ __launch_bounds__(256) void gcn_agg_chunk(
    const int* __restrict__ rs, const int* __restrict__ csrc,
    const ST* __restrict__ h1, const float* __restrict__ dinv,
    const int* __restrict__ gb, int g0, int g1, ST* __restrict__ cbuf)
{
    int wid = (blockIdx.x * 256 + threadIdx.x) >> 6;
    int lane = threadIdx.x & 63;
    int n0 = gb[g0];
    int M = gb[g1] - n0; if (M > CCAP) M = CCAP;
    if (wid >= M) return;
    int dst = n0 + wid;
    int p0 = rs[dst], p1 = rs[dst + 1];
    float dd = dinv[dst];
    float acc[13];
#pragma unroll
    for (int j = 0; j < 13; j++) acc[j] = 0.f;
    for (int pos = p0; pos < p1; ++pos) {
        int src = csrc[pos];
        float norm = dinv[src] * dd;
        const ST* hs = h1 + (size_t)src * HDIM;
#pragma unroll
        for (int j = 0; j < 13; j++) {
            int f = lane + 64 * j;
            if (f < HDIM) acc[j] = fmaf(ldv(&hs[f]), norm, acc[j]);
        }
    }
    ST* od = cbuf + (size_t)wid * HDIM;
#pragma unroll
    for (int j = 0; j < 13; j++) {
        int f = lane + 64 * j;
        if (f < HDIM) stv(&od[f], acc[j]);
    }
}

// GEMM [chunk x 780] @ [780 x 780] + bias + relu, epilogue fused max/sum pooling
// into catg (batch sorted -> per-thread row runs; atomicMax on int bits, values>=0)
template<typename ST>
__global__ __launch_bounds__(256) void gemm_pool(
    const ST* __restrict__ A, const float* __restrict__ B, const float* __restrict__ bias,
    const int* __restrict__ batch, const int* __restrict__ gb, int g0, int g1,
    float* __restrict__ catg)
{
    __shared__ float As[16][128 + 4];
    __shared__ float Bs[16][64 + 4];
    const int n0 = gb[g0];
    int M = gb[g1] - n0; if (M > CCAP) M = CCAP;
    const int bm0 = blockIdx.x * 128;
    if (bm0 >= M) return;               // block-uniform, before any sync
    const int bn0 = blockIdx.y * 64;
    const int tid = threadIdx.x;
    const int tr = tid >> 4, tc = tid & 15;
    const int a_k = tid & 15, a_r = tid >> 4;
    const int b_c = tid & 63, b_k = tid >> 6;
    float acc[8][4];
#pragma unroll
    for (int i = 0; i < 8; i++)
#pragma unroll
        for (int j = 0; j < 4; j++) acc[i][j] = 0.f;
    for (int k0 = 0; k0 < HDIM; k0 += 16) {
#pragma unroll
        for (int i = 0; i < 8; i++) {
            int r = bm0 + a_r + i * 16;
            float v = 0.f;
            if (r < M && (k0 + a_k) < HDIM) v = ldv(&A[(size_t)r * HDIM + k0 + a_k]);
            As[a_k][a_r + i * 16] = v;
        }
#pragma unroll
        for (int i = 0; i < 4; i++) {
            int kk = b_k + i * 4, col = bn0 + b_c;
            float v = 0.f;
            if ((k0 + kk) < HDIM && col < HDIM) v = B[(size_t)(k0 + kk) * HDIM + col];
            Bs[kk][b_c] = v;
        }
        __syncthreads();
#pragma unroll
        for (int kk = 0; kk < 16; kk++) {
            float4 a0 = *(const float4*)&As[kk][tr * 8];
            float4 a1 = *(const float4*)&As[kk][tr * 8 + 4];
            float4 b0 = *(const float4*)&Bs[kk][tc * 4];
            float av[8] = {a0.x,a0.y,a0.z,a0.w,a1.x,a1.y,a1.z,a1.w};
            float bv[4] = {b0.x,b0.y,b0.z,b0.w};
#pragma unroll
            for (int i = 0; i < 8; i++)
#pragma unroll
                for (int j = 0; j < 4; j++) acc[i][j] = fmaf(av[i], bv[j], acc[i][j]);
        }
        __syncthreads();
    }
    // fused pooling epilogue
    int gcur = -1;
    float rmax[4], rsum[4];
    auto flush = [&]() {
        if (gcur < 0) return;
#pragma unroll
        for (int j = 0; j < 4; j++) {
            int c = bn0 + tc * 4 + j;
            if (c < HDIM) {
                atomicMax((int*)&catg[(size_t)gcur * (2 * HDIM) + c], __float_as_int(rmax[j]));
                atomicAdd(&catg[(size_t)gcur * (2 * HDIM) + HDIM + c], rsum[j]);
            }
        }
    };
#pragma unroll
    for (int i = 0; i < 8; i++) {
        int r = bm0 + tr * 8 + i;
        if (r >= M) break;
        int g = batch[n0 + r];
        float v[4];
#pragma unroll
        for (int j = 0; j < 4; j++) {
            int c = bn0 + tc * 4 + j;
            float b = (c < HDIM) ? bias[c] : 0.f;
            v[j] = fmaxf(acc[i][j] + b, 0.f);
        }
        if (g != gcur) {
            flush();
            gcur = g;
#pragma unroll
            for (int j = 0; j < 4; j++) { rmax[j] = v[j]; rsum[j] = v[j]; }
        } else {
#pragma unroll
            for (int j = 0; j < 4; j++) { rmax[j] = fmaxf(rmax[j], v[j]); rsum[j] += v[j]; }
        }
    }
    flush();
}

__global__ void pool_div(float* __restrict__ catg, const int* __restrict__ gb)
{
    int i = blockIdx.x * 256 + threadIdx.x;
    if (i >= NG * HDIM) return;
    int g = i / HDIM, c = i - g * HDIM;
    float cnt = (float)(gb[g + 1] - gb[g]);
    catg[(size_t)g * (2 * HDIM) + HDIM + c] /= fmaxf(cnt, 1.f);
}

// ---------------- protein branch ----------------
template<typename ST>
__global__ void embed_k(const int* __restrict__ tgt, const float* __restrict__ emb,
                        ST* __restrict__ xt)
{
    int row = blockIdx.x * 2 + (threadIdx.x >> 7);
    int c = threadIdx.x & 127;
    if (row >= NG * SEQ) return;
    int idx = tgt[row];
    stv(&xt[(size_t)row * 128 + c], emb[idx * 128 + c]);
}

// NHC conv + BN + relu; POOL -> fused global-max into xp (int float-bits), else write out
template<typename ST, int CI, int CO, bool POOL>
__global__ __launch_bounds__(256) void conv1d_k(
    const ST* __restrict__ in, const float* __restrict__ wk,
    const float* __restrict__ scale, const float* __restrict__ shift,
    ST* __restrict__ out, int* __restrict__ xp, int Tin, int Tout)
{
    constexpr int TT = 64, KS_ = 16;
    constexpr int CO4 = CO / 4;
    __shared__ float in_s[TT + KS_ - 1][CI + 1];
    __shared__ float w_s[CI][CO];
    __shared__ int smax[CO];
    const int b = blockIdx.x;
    const int t0 = blockIdx.y * TT;
    const int tid = threadIdx.x;
    const int tl = tid >> 2, cg = tid & 3;
    const int co0 = cg * CO4;

    if (POOL) for (int idx = tid; idx < CO; idx += 256) smax[idx] = 0;
    const ST* inb = in + (size_t)b * Tin * CI;
    for (int idx = tid; idx < (TT + KS_ - 1) * CI; idx += 256) {
        int r = idx / CI, c = idx % CI;
        int t = t0 + r;
        in_s[r][c] = (t < Tin) ? ldv(&inb[(size_t)t * CI + c]) : 0.f;
    }
    float acc[CO4];
#pragma unroll
    for (int j = 0; j < CO4; j++) acc[j] = 0.f;
    for (int k = 0; k < KS_; k++) {
        __syncthreads();
        for (int idx = tid; idx < CI * CO; idx += 256)
            ((float*)w_s)[idx] = wk[k * CI * CO + idx];
        __syncthreads();
        for (int ci = 0; ci < CI; ci++) {
            float iv = in_s[tl + k][ci];
            const float4* wrow = (const float4*)&w_s[ci][co0];
#pragma unroll
            for (int j = 0; j < CO4 / 4; j++) {
                float4 w4 = wrow[j];
                acc[j*4+0] = fmaf(iv, w4.x, acc[j*4+0]);
                acc[j*4+1] = fmaf(iv, w4.y, acc[j*4+1]);
                acc[j*4+2] = fmaf(iv, w4.z, acc[j*4+2]);
                acc[j*4+3] = fmaf(iv, w4.w, acc[j*4+3]);
            }
        }
    }
    int t = t0 + tl;
    if (POOL) {
        if (t < Tout) {
#pragma unroll
            for (int j = 0; j < CO4; j++) {
                float v = fmaxf(fmaf(acc[j], scale[co0 + j], shift[co0 + j]), 0.f);
                atomicMax(&smax[co0 + j], __float_as_int(v));
            }
        }
        __syncthreads();
        for (int idx = tid; idx < CO; idx += 256)
            atomicMax(&xp[b * CO + idx], smax[idx]);
    } else {
        if (t < Tout) {
            ST* ob = out + ((size_t)b * Tout + t) * CO + co0;
#pragma unroll
            for (int j = 0; j < CO4; j++) {
                float v = fmaf(acc[j], scale[co0 + j], shift[co0 + j]);
                stv(&ob[j], fmaxf(v, 0.f));
            }
        }
    }
}

// ---------------- head final ----------------
__global__ void out_layer(const float* __restrict__ f2, const float* __restrict__ w,
                          const float* __restrict__ b, float* __restrict__ out)
{
    int r = (blockIdx.x * 256 + threadIdx.x) >> 6;
    int lane = threadIdx.x & 63;
    if (r >= NG) return;
    float s = 0.f;
    for (int k = lane; k < 512; k += 64) s = fmaf(f2[r * 512 + k], w[k], s);
#pragma unroll
    for (int off = 32; off >= 1; off >>= 1) s += __shfl_down(s, off);
    if (lane == 0) out[r] = s + b[0];
}

// ---------------- pipeline ----------------
template<typename ST>
static void run_pipeline(void* const* d_in, float* d_out, char* ws, hipStream_t stream)
{
    const float* x      = (const float*)d_in[0];
    const int*   ei     = (const int*)d_in[1];
    const int*   batch  = (const int*)d_in[2];
    const int*   target = (const int*)d_in[3];
    const float* gat_w  = (const float*)d_in[4];
    const float* gat_as = (const float*)d_in[5];
    const float* gat_ad = (const float*)d_in[6];
    const float* gat_b  = (const float*)d_in[7];
    const float* gcn_w  = (const float*)d_in[8];
    const float* gcn_b  = (const float*)d_in[9];
    const float* fcg1_w = (const float*)d_in[10];
    const float* fcg1_b = (const float*)d_in[11];
    const float* fcg2_w = (const float*)d_in[12];
    const float* fcg2_b = (const float*)d_in[13];
    const float* emb    = (const float*)d_in[14];
    const float* c1_w   = (const float*)d_in[15];
    const float* c1_b   = (const float*)d_in[16];
    const float* bn1_g  = (const float*)d_in[17];
    const float* bn1_b  = (const float*)d_in[18];
    const float* bn1_m  = (const float*)d_in[19];
    const float* bn1_v  = (const float*)d_in[20];
    const float* c2_w   = (const float*)d_in[21];
    const float* c2_b   = (const float*)d_in[22];
    const float* bn2_g  = (const float*)d_in[23];
    const float* bn2_b  = (const float*)d_in[24];
    const float* bn2_m  = (const float*)d_in[25];
    const float* bn2_v  = (const float*)d_in[26];
    const float* c3_w   = (const float*)d_in[27];
    const float* c3_b   = (const float*)d_in[28];
    const float* bn3_g  = (const float*)d_in[29];
    const float* bn3_b  = (const float*)d_in[30];
    const float* bn3_m  = (const float*)d_in[31];
    const float* bn3_v  = (const float*)d_in[32];
    const float* fcxt_w = (const float*)d_in[33];
    const float* fcxt_b = (const float*)d_in[34];
    const float* bnf_g  = (const float*)d_in[35];
    const float* bnf_b  = (const float*)d_in[36];
    const float* bnf_m  = (const float*)d_in[37];
    const float* bnf_v  = (const float*)d_in[38];
    const float* fc1_w  = (const float*)d_in[39];
    const float* fc1_b  = (const float*)d_in[40];
    const float* fc2_w  = (const float*)d_in[41];
    const float* fc2_b  = (const float*)d_in[42];
    const float* out_w  = (const float*)d_in[43];
    const float* out_b  = (const float*)d_in[44];

    size_t off = 0;
    auto alloc = [&](size_t bytes) -> void* {
        void* p = ws + off;
        off = (off + bytes + 255) & ~(size_t)255;
        return p;
    };
    ST*    bufA  = (ST*)alloc((size_t)N_NODES * HDIM * sizeof(ST));   // xagg/h1, embed, conv2-out
    ST*    cbuf  = (ST*)alloc((size_t)CCAP * HDIM * sizeof(ST));      // gcn chunk, conv1-out
    float* a_s   = (float*)alloc((size_t)N_NODES * HEADS * 4);
    float* a_d   = (float*)alloc((size_t)N_NODES * HEADS * 4);
    int*   deg_i = (int*)alloc((size_t)N_NODES * 4);
    int*   rs    = (int*)alloc((size_t)(N_NODES + 1) * 4);
    int*   cursor= (int*)alloc((size_t)N_NODES * 4);
    int*   csrc  = (int*)alloc((size_t)N_ETOT * 4);
    int*   bsum  = (int*)alloc(512 * 4);
    int*   gb    = (int*)alloc((NG + 1) * 4);
    float* dinv  = (float*)alloc((size_t)N_NODES * 4);
    float* catg  = (float*)alloc((size_t)NG * 2 * HDIM * 4);
    float* g1    = (float*)alloc((size_t)NG * 1500 * 4);
    float* catH  = (float*)alloc((size_t)NG * 256 * 4);
    float* f1    = (float*)alloc((size_t)NG * 1024 * 4);
    float* f2    = (float*)alloc((size_t)NG * 512 * 4);
    int*   xp    = (int*)alloc((size_t)NG * 96 * 4);
    float* Asv   = (float*)alloc((size_t)HEADS * FXD * 4);
    float* Adv   = (float*)alloc((size_t)HEADS * FXD * 4);
    float* wk1   = (float*)alloc((size_t)16 * 128 * 32 * 4);
    float* wk2   = (float*)alloc((size_t)16 * 32 * 64 * 4);
    float* wk3   = (float*)alloc((size_t)16 * 64 * 96 * 4);
    float* sc1 = (float*)alloc(32*4);  float* sh1 = (float*)alloc(32*4);
    float* sc2 = (float*)alloc(64*4);  float* sh2 = (float*)alloc(64*4);
    float* sc3 = (float*)alloc(96*4);  float* sh3 = (float*)alloc(96*4);
    float* scf = (float*)alloc(128*4); float* shf = (float*)alloc(128*4);

    const int NB = (N_NODES + 255) / 256;

    zero32<<<NB, 256, 0, stream>>>(deg_i, N_NODES);
    zero32<<<NB, 256, 0, stream>>>(cursor, N_NODES);
    zero32<<<(NG * 2 * HDIM + 255) / 256, 256, 0, stream>>>((int*)catg, NG * 2 * HDIM);
    zero32<<<(NG * 96 + 255) / 256, 256, 0, stream>>>(xp, NG * 96);

    prep_att<<<4, 256, 0, stream>>>(gat_w, gat_as, gat_ad, Asv, Adv);
    transpose_w<128, 32><<<256, 256, 0, stream>>>(c1_w, wk1);
    transpose_w<32, 64><<<128, 256, 0, stream>>>(c2_w, wk2);
    transpose_w<64, 96><<<384, 256, 0, stream>>>(c3_w, wk3);
    prep_bn<<<1, 256, 0, stream>>>(c1_b, bn1_g, bn1_b, bn1_m, bn1_v, sc1, sh1, 32, 0);
    prep_bn<<<1, 256, 0, stream>>>(c2_b, bn2_g, bn2_b, bn2_m, bn2_v, sc2, sh2, 64, 0);
    prep_bn<<<1, 256, 0, stream>>>(c3_b, bn3_g, bn3_b, bn3_m, bn3_v, sc3, sh3, 96, 0);
    prep_bn<<<1, 256, 0, stream>>>(fcxt_b, bnf_g, bnf_b, bnf_m, bnf_v, scf, shf, 128, 1);

    hist_deg<<<(N_ETOT + 255) / 256, 256, 0, stream>>>(ei, deg_i);
    scan1<<<NB, 256, 0, stream>>>(deg_i, rs, bsum, N_NODES);
    scan2<<<1, 64, 0, stream>>>(bsum, rs + N_NODES, NB);
    scan3<<<NB, 256, 0, stream>>>(rs, bsum, N_NODES);
    scatter_csr<<<(N_ETOT + 255) / 256, 256, 0, stream>>>(ei, rs, cursor, csrc);
    gbounds<<<3, 256, 0, stream>>>(batch, gb);
    dinv_k<<<NB, 256, 0, stream>>>(rs, dinv, N_NODES);

    // GAT: scores -> fused softmax+aggregate(x) -> in-place per-head transform
    att_scores<<<NB, 256, 0, stream>>>(x, Asv, Adv, a_s, a_d, N_NODES);
    gat_fused<ST><<<(N_NODES * 64) / 256, 256, 0, stream>>>(rs, csrc, a_s, a_d, x, bufA);
    gat_headgemm<ST><<<dim3((N_NODES + 63) / 64, HEADS), 256, 0, stream>>>(bufA, gat_w, gat_b);

    // GCN chunked: aggregate -> GEMM + fused pooling
    for (int c = 0; c < NCHUNK; c++) {
        gcn_agg_chunk<ST><<<(CCAP * 64) / 256, 256, 0, stream>>>(
            rs, csrc, bufA, dinv, gb, c * GPC, (c + 1) * GPC, cbuf);
        gemm_pool<ST><<<dim3(CCAP / 128, 13), 256, 0, stream>>>(
            cbuf, gcn_w, gcn_b, batch, gb, c * GPC, (c + 1) * GPC, catg);
    }
    pool_div<<<(NG * HDIM + 255) / 256, 256, 0, stream>>>(catg, gb);

    gemm_t<true, false, true><<<dim3(4, 24), 256, 0, stream>>>(
        catg, fcg1_w, fcg1_b, nullptr, nullptr, g1, NG, 1500, 2 * HDIM, 2 * HDIM, 1500, 1500);
    gemm_t<true, false, false><<<dim3(4, 2), 256, 0, stream>>>(
        g1, fcg2_w, fcg2_b, nullptr, nullptr, catH, NG, 128, 1500, 1500, 128, 256);

    // protein branch (reuses bufA / cbuf)
    embed_k<ST><<<NG * SEQ / 2, 256, 0, stream>>>(target, emb, bufA);
    conv1d_k<ST, 128, 32, false><<<dim3(NG, 16), 256, 0, stream>>>(bufA, wk1, sc1, sh1, cbuf, nullptr, 1000, 985);
    conv1d_k<ST, 32, 64, false><<<dim3(NG, 16), 256, 0, stream>>>(cbuf, wk2, sc2, sh2, bufA, nullptr, 985, 970);
    conv1d_k<ST, 64, 96, true><<<dim3(NG, 15), 256, 0, stream>>>(bufA, wk3, sc3, sh3, (ST*)nullptr, xp, 970, 955);
    gemm_t<true, true, true><<<dim3(4, 2), 256, 0, stream>>>(
        (const float*)xp, fcxt_w, fcxt_b, scf, shf, catH + 128, NG, 128, 96, 96, 128, 256);

    gemm_t<true, false, true><<<dim3(4, 16), 256, 0, stream>>>(
        catH, fc1_w, fc1_b, nullptr, nullptr, f1, NG, 1024, 256, 256, 1024, 1024);
    gemm_t<true, false, true><<<dim3(4, 8), 256, 0, stream>>>(
        f1, fc2_w, fc2_b, nullptr, nullptr, f2, NG, 512, 1024, 1024, 512, 512);
    out_layer<<<128, 256, 0, stream>>>(f2, out_w, out_b, d_out);
}

static size_t footprint(size_t esz)
{
    auto al = [](size_t b) { return (b + 255) & ~(size_t)255; };
    size_t s = 0;
    s += al((size_t)N_NODES * HDIM * esz);
    s += al((size_t)CCAP * HDIM * esz);
    s += al((size_t)N_NODES * HEADS * 4) * 2;
    s += al((size_t)N_NODES * 4) * 3 + al((size_t)(N_NODES + 1) * 4);
    s += al((size_t)N_ETOT * 4);
    s += al(512 * 4) + al((NG + 1) * 4);
    s += al((size_t)NG * 2 * HDIM * 4);
    s += al((size_t)NG * 1500 * 4) + al((size_t)NG * 256 * 4) + al((size_t)NG * 1024 * 4)
       + al((size_t)NG * 512 * 4) + al((size_t)NG * 96 * 4);
    s += al(65536 * 4) + al(32768 * 4) + al(98304 * 4);
    s += al(HEADS * FXD * 4) * 2 + 16 * 1024;
    return s + (16ull << 20);   // margin
}

extern "C" void kernel_launch(void* const* d_in, const int* in_sizes, int n_in,
                              void* d_out, int out_size, void* d_ws, size_t ws_size,
                              hipStream_t stream)
{
    if (ws_size >= footprint(sizeof(float)))
        run_pipeline<float>(d_in, (float*)d_out, (char*)d_ws, stream);
    else
        run_pipeline<bf16>(d_in, (float*)d_out, (char*)d_ws, stream);
}

// Round 8
// 7602.780 us; speedup vs baseline: 1.2313x; 1.2313x over previous
//
#include <hip/hip_runtime.h>
#include <hip/hip_bf16.h>

#define N_NODES 100000
#define N_EDGES 800000
#define N_ETOT  900000
#define HEADS   10
#define FXD     78
#define HDIM    780
#define LDK     800     // padded K-stride for MFMA operands (1600 B, 16B-aligned)
#define NG      512
#define SEQ     1000
#define CCAP    28032
#define GPC     128
#define NCHUNK  4

using bf16 = __hip_bfloat16;
using short8 = __attribute__((ext_vector_type(8))) short;
using f32x4  = __attribute__((ext_vector_type(4))) float;

__device__ __forceinline__ float ldv(const float* p){ return *p; }
__device__ __forceinline__ float ldv(const bf16* p){ return __bfloat162float(*p); }
__device__ __forceinline__ void stv(float* p, float v){ *p = v; }
__device__ __forceinline__ void stv(bf16* p, float v){ *p = __float2bfloat16(v); }

__global__ void zero32(int* a, int n){ int i = blockIdx.x*256+threadIdx.x; if(i<n) a[i]=0; }

// ---------------- generic f32 GEMM (small FCs) ----------------
template<bool HAS_BIAS, bool HAS_BN, bool RELU>
__global__ __launch_bounds__(256) void gemm_t(
    const float* __restrict__ A, const float* __restrict__ B,
    const float* __restrict__ bias, const float* __restrict__ scale,
    const float* __restrict__ shift, float* __restrict__ C,
    int M, int N, int K, int lda, int ldb, int ldc)
{
    __shared__ float As[16][128 + 4];
    __shared__ float Bs[16][64 + 4];
    const int tid = threadIdx.x;
    const int bm0 = blockIdx.x * 128, bn0 = blockIdx.y * 64;
    const int tr = tid >> 4, tc = tid & 15;
    const int a_k = tid & 15, a_r = tid >> 4;
    const int b_c = tid & 63, b_k = tid >> 6;
    float acc[8][4];
#pragma unroll
    for (int i = 0; i < 8; i++)
#pragma unroll
        for (int j = 0; j < 4; j++) acc[i][j] = 0.f;
    for (int k0 = 0; k0 < K; k0 += 16) {
#pragma unroll
        for (int i = 0; i < 8; i++) {
            int r = bm0 + a_r + i * 16;
            float v = 0.f;
            if (r < M && (k0 + a_k) < K) v = A[(size_t)r * lda + k0 + a_k];
            As[a_k][a_r + i * 16] = v;
        }
#pragma unroll
        for (int i = 0; i < 4; i++) {
            int kk = b_k + i * 4, col = bn0 + b_c;
            float v = 0.f;
            if ((k0 + kk) < K && col < N) v = B[(size_t)(k0 + kk) * ldb + col];
            Bs[kk][b_c] = v;
        }
        __syncthreads();
#pragma unroll
        for (int kk = 0; kk < 16; kk++) {
            float4 a0 = *(const float4*)&As[kk][tr * 8];
            float4 a1 = *(const float4*)&As[kk][tr * 8 + 4];
            float4 b0 = *(const float4*)&Bs[kk][tc * 4];
            float av[8] = {a0.x,a0.y,a0.z,a0.w,a1.x,a1.y,a1.z,a1.w};
            float bv[4] = {b0.x,b0.y,b0.z,b0.w};
#pragma unroll
            for (int i = 0; i < 8; i++)
#pragma unroll
                for (int j = 0; j < 4; j++) acc[i][j] = fmaf(av[i], bv[j], acc[i][j]);
        }
        __syncthreads();
    }
#pragma unroll
    for (int i = 0; i < 8; i++) {
        int r = bm0 + tr * 8 + i;
        if (r >= M) continue;
#pragma unroll
        for (int j = 0; j < 4; j++) {
            int c = bn0 + tc * 4 + j;
            if (c >= N) continue;
            float v = acc[i][j];
            if (HAS_BIAS) v += bias[c];
            if (HAS_BN)   v = v * scale[c] + shift[c];
            if (RELU)     v = fmaxf(v, 0.f);
            C[(size_t)r * ldc + c] = v;
        }
    }
}

// ---------------- prep ----------------
__global__ void prep_att(const float* __restrict__ gw, const float* __restrict__ asrc,
                         const float* __restrict__ adst, float* Asv, float* Adv)
{
    int i = blockIdx.x * 256 + threadIdx.x;
    if (i >= FXD * HEADS) return;
    int f = i / HEADS, hd = i % HEADS;
    float s = 0.f, d = 0.f;
    for (int k = 0; k < FXD; k++) {
        float w = gw[f * HDIM + hd * FXD + k];
        s = fmaf(w, asrc[hd * FXD + k], s);
        d = fmaf(w, adst[hd * FXD + k], d);
    }
    Asv[hd * FXD + f] = s;
    Adv[hd * FXD + f] = d;
}

template<int CI, int CO>
__global__ void transpose_w(const float* __restrict__ w, float* __restrict__ wk)
{
    int i = blockIdx.x * 256 + threadIdx.x;
    if (i >= CI * CO * 16) return;
    int k = i & 15, ci = (i >> 4) % CI, co = i / (16 * CI);
    wk[(k * CI + ci) * CO + co] = w[i];
}

// WT[n][k] = bf16(gcn_w[k][n]) padded to LDK cols (zeros for k>=HDIM)
__global__ void wt_k(const float* __restrict__ w, bf16* __restrict__ wt)
{
    int i = blockIdx.x * 256 + threadIdx.x;
    if (i >= HDIM * LDK) return;
    int n = i / LDK, k = i - n * LDK;
    float v = (k < HDIM) ? w[(size_t)k * HDIM + n] : 0.f;
    wt[(size_t)n * LDK + k] = __float2bfloat16(v);
}

__global__ void prep_bn(const float* bc, const float* g, const float* bb,
                        const float* m, const float* v, float* sc, float* sh, int C, int mode)
{
    int i = blockIdx.x * 256 + threadIdx.x;
    if (i >= C) return;
    float inv = rsqrtf(v[i] + 1e-5f);
    float s = g[i] * inv;
    sc[i] = s;
    sh[i] = (mode == 0) ? (bc[i] - m[i]) * s + bb[i] : (bb[i] - m[i] * s);
}

// ---------------- CSR ----------------
__global__ void hist_deg(const int* __restrict__ ei, int* __restrict__ deg_i)
{
    int e = blockIdx.x * 256 + threadIdx.x;
    if (e >= N_ETOT) return;
    int dst = (e < N_EDGES) ? ei[N_EDGES + e] : e - N_EDGES;
    atomicAdd(&deg_i[dst], 1);
}

__global__ void scan1(const int* __restrict__ in, int* __restrict__ out, int* __restrict__ bsum, int n)
{
    __shared__ int s[256];
    int t = threadIdx.x, i = blockIdx.x * 256 + t;
    int v = (i < n) ? in[i] : 0;
    s[t] = v; __syncthreads();
    for (int off = 1; off < 256; off <<= 1) {
        int u = (t >= off) ? s[t - off] : 0;
        __syncthreads(); s[t] += u; __syncthreads();
    }
    if (i < n) out[i] = s[t] - v;
    if (t == 255) bsum[blockIdx.x] = s[255];
}

__global__ void scan2(int* __restrict__ bsum, int* __restrict__ total, int nb)
{
    if (threadIdx.x == 0 && blockIdx.x == 0) {
        int run = 0;
        for (int b = 0; b < nb; b++) { int t = bsum[b]; bsum[b] = run; run += t; }
        *total = run;
    }
}

__global__ void scan3(int* __restrict__ rs, const int* __restrict__ bsum, int n)
{
    int i = blockIdx.x * 256 + threadIdx.x;
    if (i < n) rs[i] += bsum[i >> 8];
}

__global__ void scatter_csr(const int* __restrict__ ei, const int* __restrict__ rs,
                            int* __restrict__ cursor, int* __restrict__ csr_src)
{
    int e = blockIdx.x * 256 + threadIdx.x;
    if (e >= N_ETOT) return;
    int src, dst;
    if (e < N_EDGES) { src = ei[e]; dst = ei[N_EDGES + e]; }
    else             { src = dst = e - N_EDGES; }
    int ofs = atomicAdd(&cursor[dst], 1);
    csr_src[rs[dst] + ofs] = src;
}

__global__ void gbounds(const int* __restrict__ batch, int* __restrict__ gb)
{
    int g = blockIdx.x * 256 + threadIdx.x;
    if (g > NG) return;
    int lo = 0, hi = N_NODES;
    while (lo < hi) { int mid = (lo + hi) >> 1; if (batch[mid] < g) lo = mid + 1; else hi = mid; }
    gb[g] = lo;
}

__global__ void dinv_k(const int* __restrict__ rs, float* __restrict__ dinv, int n)
{
    int i = blockIdx.x * 256 + threadIdx.x;
    if (i < n) dinv[i] = rsqrtf((float)(rs[i + 1] - rs[i]));
}

// ---------------- GAT ----------------
__global__ void att_scores(const float* __restrict__ x, const float* __restrict__ Asv,
                           const float* __restrict__ Adv, float* as_o, float* ad_o, int N)
{
    int n = blockIdx.x * 256 + threadIdx.x;
    if (n >= N) return;
    float xr[FXD];
#pragma unroll
    for (int k = 0; k < FXD; k++) xr[k] = x[n * FXD + k];
#pragma unroll
    for (int hd = 0; hd < HEADS; hd++) {
        float s = 0.f, d = 0.f;
#pragma unroll
        for (int k = 0; k < FXD; k++) {
            s = fmaf(xr[k], Asv[hd * FXD + k], s);
            d = fmaf(xr[k], Adv[hd * FXD + k], d);
        }
        as_o[n * HEADS + hd] = s;
        ad_o[n * HEADS + hd] = d;
    }
}

template<typename ST>
__global__ __launch_bounds__(256) void gat_fused(
    const int* __restrict__ rs, const int* __restrict__ csrc,
    const float* __restrict__ as_, const float* __restrict__ ad_,
    const float* __restrict__ x, ST* __restrict__ xagg)
{
    int wid = (blockIdx.x * 256 + threadIdx.x) >> 6;
    int lane = threadIdx.x & 63;
    if (wid >= N_NODES) return;
    int p0 = rs[wid], p1 = rs[wid + 1];
    float m = -1e30f, z = 0.f, ad = 0.f, zinv = 0.f;
    if (lane < HEADS) {
        ad = ad_[wid * HEADS + lane];
        for (int pos = p0; pos < p1; ++pos) {
            float v = as_[csrc[pos] * HEADS + lane] + ad;
            v = v >= 0.f ? v : 0.2f * v;
            m = fmaxf(m, v);
        }
        for (int pos = p0; pos < p1; ++pos) {
            float v = as_[csrc[pos] * HEADS + lane] + ad;
            v = v >= 0.f ? v : 0.2f * v;
            z += __expf(v - m);
        }
        zinv = 1.f / z;
    }
    int hdj[13], kj[13];
#pragma unroll
    for (int j = 0; j < 13; j++) {
        int f = lane + 64 * j;
        hdj[j] = (f < HDIM) ? f / FXD : 0;
        kj[j]  = (f < HDIM) ? f % FXD : 0;
    }
    float acc[13];
#pragma unroll
    for (int j = 0; j < 13; j++) acc[j] = 0.f;
    for (int pos = p0; pos < p1; ++pos) {
        int src = csrc[pos];
        float sc = 0.f;
        if (lane < HEADS) {
            float v = as_[src * HEADS + lane] + ad;
            v = v >= 0.f ? v : 0.2f * v;
            sc = __expf(v - m) * zinv;
        }
        const float* xs = x + (size_t)src * FXD;
#pragma unroll
        for (int j = 0; j < 13; j++) {
            float a = __shfl(sc, hdj[j]);
            int f = lane + 64 * j;
            if (f < HDIM) acc[j] = fmaf(a, xs[kj[j]], acc[j]);
        }
    }
    ST* od = xagg + (size_t)wid * HDIM;
#pragma unroll
    for (int j = 0; j < 13; j++) {
        int f = lane + 64 * j;
        if (f < HDIM) stv(&od[f], acc[j]);
    }
}

template<typename ST>
__global__ __launch_bounds__(256) void gat_headgemm(
    ST* __restrict__ h, const float* __restrict__ W, const float* __restrict__ bias)
{
    __shared__ float As[64][80];
    __shared__ float Bs[FXD][80];
    const int bm0 = blockIdx.x * 64;
    const int hd = blockIdx.y;
    const int tid = threadIdx.x;
    for (int idx = tid; idx < FXD * FXD; idx += 256) {
        int k = idx / FXD, f = idx % FXD;
        Bs[k][f] = W[k * HDIM + hd * FXD + f];
    }
    for (int idx = tid; idx < 64 * FXD; idx += 256) {
        int rl = idx / FXD, c = idx % FXD;
        int r = bm0 + rl;
        As[rl][c] = (r < N_NODES) ? ldv(&h[(size_t)r * HDIM + hd * FXD + c]) : 0.f;
    }
    __syncthreads();
    const int rl = tid >> 2, cg = tid & 3;
    float acc[20];
#pragma unroll
    for (int j = 0; j < 20; j++) acc[j] = 0.f;
    for (int k = 0; k < FXD; k++) {
        float a = As[rl][k];
#pragma unroll
        for (int j = 0; j < 20; j++) {
            int c = cg + 4 * j;
            if (c < FXD) acc[j] = fmaf(a, Bs[k][c], acc[j]);
        }
    }
    int r = bm0 + rl;
    if (r < N_NODES) {
#pragma unroll
        for (int j = 0; j < 20; j++) {
            int c = cg + 4 * j;
            if (c < FXD)
                stv(&h[(size_t)r * HDIM + hd * FXD + c],
                    fmaxf(acc[j] + bias[hd * FXD + c], 0.f));
        }
    }
}

// ---------------- GCN chunked ----------------
// writes cbuf rows with stride LDK; pad cols [HDIM,LDK) zeroed
template<typename ST>
__global__ __launch_bounds__(256) void gcn_agg_chunk(
    const int* __restrict__ rs, const int* __restrict__ csrc,
    const ST* __restrict__ h1, const float* __restrict__ dinv,
    const int* __restrict__ gb, int g0, int g1, bf16* __restrict__ cbuf)
{
    int wid = (blockIdx.x * 256 + threadIdx.x) >> 6;
    int lane = threadIdx.x & 63;
    int n0 = gb[g0];
    int M = gb[g1] - n0; if (M > CCAP) M = CCAP;
    if (wid >= M) return;
    int dst = n0 + wid;
    int p0 = rs[dst], p1 = rs[dst + 1];
    float dd = dinv[dst];
    float acc[13];
#pragma unroll
    for (int j = 0; j < 13; j++) acc[j] = 0.f;
    for (int pos = p0; pos < p1; ++pos) {
        int src = csrc[pos];
        float norm = dinv[src] * dd;
        const ST* hs = h1 + (size_t)src * HDIM;
#pragma unroll
        for (int j = 0; j < 13; j++) {
            int f = lane + 64 * j;
            if (f < HDIM) acc[j] = fmaf(ldv(&hs[f]), norm, acc[j]);
        }
    }
    bf16* od = cbuf + (size_t)wid * LDK;
#pragma unroll
    for (int j = 0; j < 13; j++) {
        int f = lane + 64 * j;
        if (f < HDIM)      stv(&od[f], acc[j]);
        else if (f < LDK)  stv(&od[f], 0.f);
    }
}

// MFMA GEMM [M x HDIM] @ WT^T + bias + relu, fused max/sum pooling into catg.
// A bf16 [rows][LDK], WT bf16 [HDIM][LDK], both zero-padded to LDK.
// BM=128 BN=64 BK=32, 4 waves. grid: x = col-panel (fast), y = row-block.
__global__ __launch_bounds__(256) void gemm_pool_mfma(
    const bf16* __restrict__ A, const bf16* __restrict__ WT, const float* __restrict__ bias,
    const int* __restrict__ batch, const int* __restrict__ gb, int g0, int g1,
    float* __restrict__ catg)
{
    __shared__ unsigned short As[128][40];   // stride 80 B (16B-aligned rows)
    __shared__ unsigned short Bs[64][40];
    const int n0 = gb[g0];
    int M = gb[g1] - n0; if (M > CCAP) M = CCAP;
    const int bm0 = blockIdx.y * 128;
    if (bm0 >= M) return;
    const int bn0 = blockIdx.x * 64;
    const int tid = threadIdx.x;
    const int lane = tid & 63, w = tid >> 6;
    const int wr = (w >> 1) * 64, wc = (w & 1) * 32;
    const int fr_i = lane & 15, fk = (lane >> 4) * 8;

    f32x4 acc[4][2];
#pragma unroll
    for (int i = 0; i < 4; i++)
#pragma unroll
        for (int j = 0; j < 2; j++) acc[i][j] = (f32x4)(0.f);

    const int a_row = tid >> 1, a_ks = (tid & 1) * 16;
    const int b_col = tid >> 2, b_ks = (tid & 3) * 8;
    const bool rok = (bm0 + a_row) < M;                 // FIX: global row gate
    const unsigned short* ga =
        (const unsigned short*)A + (size_t)(bm0 + a_row) * LDK + a_ks;  // FIX: + bm0
    const int gc = bn0 + b_col;
    const unsigned short* gw = (const unsigned short*)WT + (size_t)gc * LDK + b_ks;
    const short8 zv = (short8)(0);

    for (int k0 = 0; k0 < LDK; k0 += 32) {
#pragma unroll
        for (int h = 0; h < 2; h++)
            *(short8*)&As[a_row][a_ks + h * 8] =
                rok ? *(const short8*)(ga + k0 + h * 8) : zv;
        *(short8*)&Bs[b_col][b_ks] =
            (gc < HDIM) ? *(const short8*)(gw + k0) : zv;
        __syncthreads();
        short8 af[4], bf[2];
#pragma unroll
        for (int fr = 0; fr < 4; fr++)
            af[fr] = *(const short8*)&As[wr + fr * 16 + fr_i][fk];
#pragma unroll
        for (int fc = 0; fc < 2; fc++)
            bf[fc] = *(const short8*)&Bs[wc + fc * 16 + fr_i][fk];
#pragma unroll
        for (int fr = 0; fr < 4; fr++)
#pragma unroll
            for (int fc = 0; fc < 2; fc++)
                acc[fr][fc] = __builtin_amdgcn_mfma_f32_16x16x32_bf16(
                    af[fr], bf[fc], acc[fr][fc], 0, 0, 0);
        __syncthreads();
    }

    // epilogue: bias+relu, run-length pooling over each lane's 4 consecutive rows
#pragma unroll
    for (int fr = 0; fr < 4; fr++) {
        int r0 = bm0 + wr + fr * 16 + (lane >> 4) * 4;
        int gg[4]; bool valid[4];
#pragma unroll
        for (int j = 0; j < 4; j++) {
            int lr = r0 + j;
            valid[j] = lr < M;
            gg[j] = valid[j] ? batch[n0 + lr] : -1;
        }
#pragma unroll
        for (int fc = 0; fc < 2; fc++) {
            int c = bn0 + wc + fc * 16 + fr_i;
            if (c >= HDIM) continue;
            float bc = bias[c];
            int gcur = -1; float vmax = 0.f, vsum = 0.f;
#pragma unroll
            for (int j = 0; j < 4; j++) {
                if (!valid[j]) break;
                float v = fmaxf(acc[fr][fc][j] + bc, 0.f);
                if (gg[j] != gcur) {
                    if (gcur >= 0) {
                        atomicMax((int*)&catg[(size_t)gcur * (2 * HDIM) + c], __float_as_int(vmax));
                        atomicAdd(&catg[(size_t)gcur * (2 * HDIM) + HDIM + c], vsum);
                    }
                    gcur = gg[j]; vmax = v; vsum = v;
                } else { vmax = fmaxf(vmax, v); vsum += v; }
            }
            if (gcur >= 0) {
                atomicMax((int*)&catg[(size_t)gcur * (2 * HDIM) + c], __float_as_int(vmax));
                atomicAdd(&catg[(size_t)gcur * (2 * HDIM) + HDIM + c], vsum);
            }
        }
    }
}

__global__ void pool_div(float* __restrict__ catg, const int* __restrict__ gb)
{
    int i = blockIdx.x * 256 + threadIdx.x;
    if (i >= NG * HDIM) return;
    int g = i / HDIM, c = i - g * HDIM;
    float cnt = (float)(gb[g + 1] - gb[g]);
    catg[(size_t)g * (2 * HDIM) + HDIM + c] /= fmaxf(cnt, 1.f);
}

// ---------------- protein branch (bf16 buffers) ----------------
__global__ void embed_k(const int* __restrict__ tgt, const float* __restrict__ emb,
                        bf16* __restrict__ xt)
{
    int row = blockIdx.x * 2 + (threadIdx.x >> 7);
    int c = threadIdx.x & 127;
    if (row >= NG * SEQ) return;
    int idx = tgt[row];
    stv(&xt[(size_t)row * 128 + c], emb[idx * 128 + c]);
}

template<int CI, int CO, bool POOL>
__global__ __launch_bounds__(256) void conv1d_k(
    const bf16* __restrict__ in, const float* __restrict__ wk,
    const float* __restrict__ scale, const float* __restrict__ shift,
    bf16* __restrict__ out, int* __restrict__ xp, int Tin, int Tout)
{
    constexpr int TT = 64, KS_ = 16;
    constexpr int CO4 = CO / 4;
    __shared__ float in_s[TT + KS_ - 1][CI + 1];
    __shared__ float w_s[CI][CO];
    __shared__ int smax[CO];
    const int b = blockIdx.x;
    const int t0 = blockIdx.y * TT;
    const int tid = threadIdx.x;
    const int tl = tid >> 2, cg = tid & 3;
    const int co0 = cg * CO4;

    if (POOL) for (int idx = tid; idx < CO; idx += 256) smax[idx] = 0;
    const bf16* inb = in + (size_t)b * Tin * CI;
    for (int idx = tid; idx < (TT + KS_ - 1) * CI; idx += 256) {
        int r = idx / CI, c = idx % CI;
        int t = t0 + r;
        in_s[r][c] = (t < Tin) ? ldv(&inb[(size_t)t * CI + c]) : 0.f;
    }
    float acc[CO4];
#pragma unroll
    for (int j = 0; j < CO4; j++) acc[j] = 0.f;
    for (int k = 0; k < KS_; k++) {
        __syncthreads();
        for (int idx = tid; idx < CI * CO; idx += 256)
            ((float*)w_s)[idx] = wk[k * CI * CO + idx];
        __syncthreads();
        for (int ci = 0; ci < CI; ci++) {
            float iv = in_s[tl + k][ci];
            const float4* wrow = (const float4*)&w_s[ci][co0];
#pragma unroll
            for (int j = 0; j < CO4 / 4; j++) {
                float4 w4 = wrow[j];
                acc[j*4+0] = fmaf(iv, w4.x, acc[j*4+0]);
                acc[j*4+1] = fmaf(iv, w4.y, acc[j*4+1]);
                acc[j*4+2] = fmaf(iv, w4.z, acc[j*4+2]);
                acc[j*4+3] = fmaf(iv, w4.w, acc[j*4+3]);
            }
        }
    }
    int t = t0 + tl;
    if (POOL) {
        if (t < Tout) {
#pragma unroll
            for (int j = 0; j < CO4; j++) {
                float v = fmaxf(fmaf(acc[j], scale[co0 + j], shift[co0 + j]), 0.f);
                atomicMax(&smax[co0 + j], __float_as_int(v));
            }
        }
        __syncthreads();
        for (int idx = tid; idx < CO; idx += 256)
            atomicMax(&xp[b * CO + idx], smax[idx]);
    } else {
        if (t < Tout) {
            bf16* ob = out + ((size_t)b * Tout + t) * CO + co0;
#pragma unroll
            for (int j = 0; j < CO4; j++) {
                float v = fmaf(acc[j], scale[co0 + j], shift[co0 + j]);
                stv(&ob[j], fmaxf(v, 0.f));
            }
        }
    }
}

// ---------------- head final ----------------
__global__ void out_layer(const float* __restrict__ f2, const float* __restrict__ w,
                          const float* __restrict__ b, float* __restrict__ out)
{
    int r = (blockIdx.x * 256 + threadIdx.x) >> 6;
    int lane = threadIdx.x & 63;
    if (r >= NG) return;
    float s = 0.f;
    for (int k = lane; k < 512; k += 64) s = fmaf(f2[r * 512 + k], w[k], s);
#pragma unroll
    for (int off = 32; off >= 1; off >>= 1) s += __shfl_down(s, off);
    if (lane == 0) out[r] = s + b[0];
}

// ---------------- pipeline ----------------
template<typename ST>
static void run_pipeline(void* const* d_in, float* d_out, char* ws, hipStream_t stream)
{
    const float* x      = (const float*)d_in[0];
    const int*   ei     = (const int*)d_in[1];
    const int*   batch  = (const int*)d_in[2];
    const int*   target = (const int*)d_in[3];
    const float* gat_w  = (const float*)d_in[4];
    const float* gat_as = (const float*)d_in[5];
    const float* gat_ad = (const float*)d_in[6];
    const float* gat_b  = (const float*)d_in[7];
    const float* gcn_w  = (const float*)d_in[8];
    const float* gcn_b  = (const float*)d_in[9];
    const float* fcg1_w = (const float*)d_in[10];
    const float* fcg1_b = (const float*)d_in[11];
    const float* fcg2_w = (const float*)d_in[12];
    const float* fcg2_b = (const float*)d_in[13];
    const float* emb    = (const float*)d_in[14];
    const float* c1_w   = (const float*)d_in[15];
    const float* c1_b   = (const float*)d_in[16];
    const float* bn1_g  = (const float*)d_in[17];
    const float* bn1_b  = (const float*)d_in[18];
    const float* bn1_m  = (const float*)d_in[19];
    const float* bn1_v  = (const float*)d_in[20];
    const float* c2_w   = (const float*)d_in[21];
    const float* c2_b   = (const float*)d_in[22];
    const float* bn2_g  = (const float*)d_in[23];
    const float* bn2_b  = (const float*)d_in[24];
    const float* bn2_m  = (const float*)d_in[25];
    const float* bn2_v  = (const float*)d_in[26];
    const float* c3_w   = (const float*)d_in[27];
    const float* c3_b   = (const float*)d_in[28];
    const float* bn3_g  = (const float*)d_in[29];
    const float* bn3_b  = (const float*)d_in[30];
    const float* bn3_m  = (const float*)d_in[31];
    const float* bn3_v  = (const float*)d_in[32];
    const float* fcxt_w = (const float*)d_in[33];
    const float* fcxt_b = (const float*)d_in[34];
    const float* bnf_g  = (const float*)d_in[35];
    const float* bnf_b  = (const float*)d_in[36];
    const float* bnf_m  = (const float*)d_in[37];
    const float* bnf_v  = (const float*)d_in[38];
    const float* fc1_w  = (const float*)d_in[39];
    const float* fc1_b  = (const float*)d_in[40];
    const float* fc2_w  = (const float*)d_in[41];
    const float* fc2_b  = (const float*)d_in[42];
    const float* out_w  = (const float*)d_in[43];
    const float* out_b  = (const float*)d_in[44];

    size_t off = 0;
    auto alloc = [&](size_t bytes) -> void* {
        void* p = ws + off;
        off = (off + bytes + 255) & ~(size_t)255;
        return p;
    };
    ST*    bufA  = (ST*)alloc((size_t)N_NODES * HDIM * sizeof(ST));   // xagg/h1; embed/conv2-out (as bf16)
    bf16*  cbuf  = (bf16*)alloc((size_t)CCAP * LDK * sizeof(bf16));   // gcn chunk (LDK-padded); conv1-out
    bf16*  WT    = (bf16*)alloc((size_t)HDIM * LDK * sizeof(bf16));
    float* a_s   = (float*)alloc((size_t)N_NODES * HEADS * 4);
    float* a_d   = (float*)alloc((size_t)N_NODES * HEADS * 4);
    int*   deg_i = (int*)alloc((size_t)N_NODES * 4);
    int*   rs    = (int*)alloc((size_t)(N_NODES + 1) * 4);
    int*   cursor= (int*)alloc((size_t)N_NODES * 4);
    int*   csrc  = (int*)alloc((size_t)N_ETOT * 4);
    int*   bsum  = (int*)alloc(512 * 4);
    int*   gb    = (int*)alloc((NG + 1) * 4);
    float* dinv  = (float*)alloc((size_t)N_NODES * 4);
    float* catg  = (float*)alloc((size_t)NG * 2 * HDIM * 4);
    float* g1    = (float*)alloc((size_t)NG * 1500 * 4);
    float* catH  = (float*)alloc((size_t)NG * 256 * 4);
    float* f1    = (float*)alloc((size_t)NG * 1024 * 4);
    float* f2    = (float*)alloc((size_t)NG * 512 * 4);
    int*   xp    = (int*)alloc((size_t)NG * 96 * 4);
    float* Asv   = (float*)alloc((size_t)HEADS * FXD * 4);
    float* Adv   = (float*)alloc((size_t)HEADS * FXD * 4);
    float* wk1   = (float*)alloc((size_t)16 * 128 * 32 * 4);
    float* wk2   = (float*)alloc((size_t)16 * 32 * 64 * 4);
    float* wk3   = (float*)alloc((size_t)16 * 64 * 96 * 4);
    float* sc1 = (float*)alloc(32*4);  float* sh1 = (float*)alloc(32*4);
    float* sc2 = (float*)alloc(64*4);  float* sh2 = (float*)alloc(64*4);
    float* sc3 = (float*)alloc(96*4);  float* sh3 = (float*)alloc(96*4);
    float* scf = (float*)alloc(128*4); float* shf = (float*)alloc(128*4);

    const int NB = (N_NODES + 255) / 256;

    zero32<<<NB, 256, 0, stream>>>(deg_i, N_NODES);
    zero32<<<NB, 256, 0, stream>>>(cursor, N_NODES);
    zero32<<<(NG * 2 * HDIM + 255) / 256, 256, 0, stream>>>((int*)catg, NG * 2 * HDIM);
    zero32<<<(NG * 96 + 255) / 256, 256, 0, stream>>>(xp, NG * 96);

    prep_att<<<4, 256, 0, stream>>>(gat_w, gat_as, gat_ad, Asv, Adv);
    wt_k<<<(HDIM * LDK + 255) / 256, 256, 0, stream>>>(gcn_w, WT);
    transpose_w<128, 32><<<256, 256, 0, stream>>>(c1_w, wk1);
    transpose_w<32, 64><<<128, 256, 0, stream>>>(c2_w, wk2);
    transpose_w<64, 96><<<384, 256, 0, stream>>>(c3_w, wk3);
    prep_bn<<<1, 256, 0, stream>>>(c1_b, bn1_g, bn1_b, bn1_m, bn1_v, sc1, sh1, 32, 0);
    prep_bn<<<1, 256, 0, stream>>>(c2_b, bn2_g, bn2_b, bn2_m, bn2_v, sc2, sh2, 64, 0);
    prep_bn<<<1, 256, 0, stream>>>(c3_b, bn3_g, bn3_b, bn3_m, bn3_v, sc3, sh3, 96, 0);
    prep_bn<<<1, 256, 0, stream>>>(fcxt_b, bnf_g, bnf_b, bnf_m, bnf_v, scf, shf, 128, 1);

    hist_deg<<<(N_ETOT + 255) / 256, 256, 0, stream>>>(ei, deg_i);
    scan1<<<NB, 256, 0, stream>>>(deg_i, rs, bsum, N_NODES);
    scan2<<<1, 64, 0, stream>>>(bsum, rs + N_NODES, NB);
    scan3<<<NB, 256, 0, stream>>>(rs, bsum, N_NODES);
    scatter_csr<<<(N_ETOT + 255) / 256, 256, 0, stream>>>(ei, rs, cursor, csrc);
    gbounds<<<3, 256, 0, stream>>>(batch, gb);
    dinv_k<<<NB, 256, 0, stream>>>(rs, dinv, N_NODES);

    // GAT
    att_scores<<<NB, 256, 0, stream>>>(x, Asv, Adv, a_s, a_d, N_NODES);
    gat_fused<ST><<<(N_NODES * 64) / 256, 256, 0, stream>>>(rs, csrc, a_s, a_d, x, bufA);
    gat_headgemm<ST><<<dim3((N_NODES + 63) / 64, HEADS), 256, 0, stream>>>(bufA, gat_w, gat_b);

    // GCN chunked: aggregate -> MFMA GEMM + fused pooling
    for (int c = 0; c < NCHUNK; c++) {
        gcn_agg_chunk<ST><<<(CCAP * 64) / 256, 256, 0, stream>>>(
            rs, csrc, bufA, dinv, gb, c * GPC, (c + 1) * GPC, cbuf);
        gemm_pool_mfma<<<dim3(13, CCAP / 128), 256, 0, stream>>>(
            cbuf, WT, gcn_b, batch, gb, c * GPC, (c + 1) * GPC, catg);
    }
    pool_div<<<(NG * HDIM + 255) / 256, 256, 0, stream>>>(catg, gb);

    gemm_t<true, false, true><<<dim3(4, 24), 256, 0, stream>>>(
        catg, fcg1_w, fcg1_b, nullptr, nullptr, g1, NG, 1500, 2 * HDIM, 2 * HDIM, 1500, 1500);
    gemm_t<true, false, false><<<dim3(4, 2), 256, 0, stream>>>(
        g1, fcg2_w, fcg2_b, nullptr, nullptr, catH, NG, 128, 1500, 1500, 128, 256);

    // protein branch (bf16 buffers; reuses bufA / cbuf storage)
    bf16* pbufA = (bf16*)bufA;
    embed_k<<<NG * SEQ / 2, 256, 0, stream>>>(target, emb, pbufA);
    conv1d_k<128, 32, false><<<dim3(NG, 16), 256, 0, stream>>>(pbufA, wk1, sc1, sh1, cbuf, nullptr, 1000, 985);
    conv1d_k<32, 64, false><<<dim3(NG, 16), 256, 0, stream>>>(cbuf, wk2, sc2, sh2, pbufA, nullptr, 985, 970);
    conv1d_k<64, 96, true><<<dim3(NG, 15), 256, 0, stream>>>(pbufA, wk3, sc3, sh3, (bf16*)nullptr, xp, 970, 955);
    gemm_t<true, true, true><<<dim3(4, 2), 256, 0, stream>>>(
        (const float*)xp, fcxt_w, fcxt_b, scf, shf, catH + 128, NG, 128, 96, 96, 128, 256);

    gemm_t<true, false, true><<<dim3(4, 16), 256, 0, stream>>>(
        catH, fc1_w, fc1_b, nullptr, nullptr, f1, NG, 1024, 256, 256, 1024, 1024);
    gemm_t<true, false, true><<<dim3(4, 8), 256, 0, stream>>>(
        f1, fc2_w, fc2_b, nullptr, nullptr, f2, NG, 512, 1024, 1024, 512, 512);
    out_layer<<<128, 256, 0, stream>>>(f2, out_w, out_b, d_out);
}

static size_t footprint(size_t esz)
{
    auto al = [](size_t b) { return (b + 255) & ~(size_t)255; };
    size_t s = 0;
    s += al((size_t)N_NODES * HDIM * esz);
    s += al((size_t)CCAP * LDK * 2);
    s += al((size_t)HDIM * LDK * 2);
    s += al((size_t)N_NODES * HEADS * 4) * 2;
    s += al((size_t)N_NODES * 4) * 3 + al((size_t)(N_NODES + 1) * 4);
    s += al((size_t)N_ETOT * 4);
    s += al(512 * 4) + al((NG + 1) * 4);
    s += al((size_t)NG * 2 * HDIM * 4);
    s += al((size_t)NG * 1500 * 4) + al((size_t)NG * 256 * 4) + al((size_t)NG * 1024 * 4)
       + al((size_t)NG * 512 * 4) + al((size_t)NG * 96 * 4);
    s += al(65536 * 4) + al(32768 * 4) + al(98304 * 4);
    s += al(HEADS * FXD * 4) * 2 + 16 * 1024;
    return s + (16ull << 20);
}

extern "C" void kernel_launch(void* const* d_in, const int* in_sizes, int n_in,
                              void* d_out, int out_size, void* d_ws, size_t ws_size,
                              hipStream_t stream)
{
    if (ws_size >= footprint(sizeof(float)))
        run_pipeline<float>(d_in, (float*)d_out, (char*)d_ws, stream);
    else
        run_pipeline<bf16>(d_in, (float*)d_out, (char*)d_ws, stream);
}

// Round 9
// 4024.547 us; speedup vs baseline: 2.3261x; 1.8891x over previous
//
#include <hip/hip_runtime.h>
#include <hip/hip_bf16.h>

#define N_NODES 100000
#define N_EDGES 800000
#define N_ETOT  900000
#define HEADS   10
#define FXD     78
#define HDIM    780
#define LDK     800     // padded K-stride for GCN MFMA operands (1600 B, 16B-aligned)
#define NG      512
#define SEQ     1000
#define CCAP    28032
#define GPC     128
#define NCHUNK  4

using bf16 = __hip_bfloat16;
using short8 = __attribute__((ext_vector_type(8))) short;
using f32x4  = __attribute__((ext_vector_type(4))) float;

__device__ __forceinline__ float ldv(const float* p){ return *p; }
__device__ __forceinline__ float ldv(const bf16* p){ return __bfloat162float(*p); }
__device__ __forceinline__ void stv(float* p, float v){ *p = v; }
__device__ __forceinline__ void stv(bf16* p, float v){ *p = __float2bfloat16(v); }

__global__ void zero32(int* a, int n){ int i = blockIdx.x*256+threadIdx.x; if(i<n) a[i]=0; }

// ---------------- generic f32 GEMM (small FCs) ----------------
template<bool HAS_BIAS, bool HAS_BN, bool RELU>
__global__ __launch_bounds__(256) void gemm_t(
    const float* __restrict__ A, const float* __restrict__ B,
    const float* __restrict__ bias, const float* __restrict__ scale,
    const float* __restrict__ shift, float* __restrict__ C,
    int M, int N, int K, int lda, int ldb, int ldc)
{
    __shared__ float As[16][128 + 4];
    __shared__ float Bs[16][64 + 4];
    const int tid = threadIdx.x;
    const int bm0 = blockIdx.x * 128, bn0 = blockIdx.y * 64;
    const int tr = tid >> 4, tc = tid & 15;
    const int a_k = tid & 15, a_r = tid >> 4;
    const int b_c = tid & 63, b_k = tid >> 6;
    float acc[8][4];
#pragma unroll
    for (int i = 0; i < 8; i++)
#pragma unroll
        for (int j = 0; j < 4; j++) acc[i][j] = 0.f;
    for (int k0 = 0; k0 < K; k0 += 16) {
#pragma unroll
        for (int i = 0; i < 8; i++) {
            int r = bm0 + a_r + i * 16;
            float v = 0.f;
            if (r < M && (k0 + a_k) < K) v = A[(size_t)r * lda + k0 + a_k];
            As[a_k][a_r + i * 16] = v;
        }
#pragma unroll
        for (int i = 0; i < 4; i++) {
            int kk = b_k + i * 4, col = bn0 + b_c;
            float v = 0.f;
            if ((k0 + kk) < K && col < N) v = B[(size_t)(k0 + kk) * ldb + col];
            Bs[kk][b_c] = v;
        }
        __syncthreads();
#pragma unroll
        for (int kk = 0; kk < 16; kk++) {
            float4 a0 = *(const float4*)&As[kk][tr * 8];
            float4 a1 = *(const float4*)&As[kk][tr * 8 + 4];
            float4 b0 = *(const float4*)&Bs[kk][tc * 4];
            float av[8] = {a0.x,a0.y,a0.z,a0.w,a1.x,a1.y,a1.z,a1.w};
            float bv[4] = {b0.x,b0.y,b0.z,b0.w};
#pragma unroll
            for (int i = 0; i < 8; i++)
#pragma unroll
                for (int j = 0; j < 4; j++) acc[i][j] = fmaf(av[i], bv[j], acc[i][j]);
        }
        __syncthreads();
    }
#pragma unroll
    for (int i = 0; i < 8; i++) {
        int r = bm0 + tr * 8 + i;
        if (r >= M) continue;
#pragma unroll
        for (int j = 0; j < 4; j++) {
            int c = bn0 + tc * 4 + j;
            if (c >= N) continue;
            float v = acc[i][j];
            if (HAS_BIAS) v += bias[c];
            if (HAS_BN)   v = v * scale[c] + shift[c];
            if (RELU)     v = fmaxf(v, 0.f);
            C[(size_t)r * ldc + c] = v;
        }
    }
}

// ---------------- prep ----------------
__global__ void prep_att(const float* __restrict__ gw, const float* __restrict__ asrc,
                         const float* __restrict__ adst, float* Asv, float* Adv)
{
    int i = blockIdx.x * 256 + threadIdx.x;
    if (i >= FXD * HEADS) return;
    int f = i / HEADS, hd = i % HEADS;
    float s = 0.f, d = 0.f;
    for (int k = 0; k < FXD; k++) {
        float w = gw[f * HDIM + hd * FXD + k];
        s = fmaf(w, asrc[hd * FXD + k], s);
        d = fmaf(w, adst[hd * FXD + k], d);
    }
    Asv[hd * FXD + f] = s;
    Adv[hd * FXD + f] = d;
}

// conv weights: wtc[co][kk*CI+ci] = bf16(w[co][ci][kk])  (OIH -> [co][K] row-major)
template<int CI, int CO>
__global__ void prep_wt_conv(const float* __restrict__ w, bf16* __restrict__ wtc)
{
    int i = blockIdx.x * 256 + threadIdx.x;
    if (i >= CO * CI * 16) return;
    int co = i / (CI * 16);
    int k  = i % (CI * 16);
    int kk = k / CI, ci = k % CI;
    wtc[i] = __float2bfloat16(w[(co * CI + ci) * 16 + kk]);
}

// WT[n][k] = bf16(gcn_w[k][n]) padded to LDK cols (zeros for k>=HDIM)
__global__ void wt_k(const float* __restrict__ w, bf16* __restrict__ wt)
{
    int i = blockIdx.x * 256 + threadIdx.x;
    if (i >= HDIM * LDK) return;
    int n = i / LDK, k = i - n * LDK;
    float v = (k < HDIM) ? w[(size_t)k * HDIM + n] : 0.f;
    wt[(size_t)n * LDK + k] = __float2bfloat16(v);
}

__global__ void prep_bn(const float* bc, const float* g, const float* bb,
                        const float* m, const float* v, float* sc, float* sh, int C, int mode)
{
    int i = blockIdx.x * 256 + threadIdx.x;
    if (i >= C) return;
    float inv = rsqrtf(v[i] + 1e-5f);
    float s = g[i] * inv;
    sc[i] = s;
    sh[i] = (mode == 0) ? (bc[i] - m[i]) * s + bb[i] : (bb[i] - m[i] * s);
}

// ---------------- CSR ----------------
__global__ void hist_deg(const int* __restrict__ ei, int* __restrict__ deg_i)
{
    int e = blockIdx.x * 256 + threadIdx.x;
    if (e >= N_ETOT) return;
    int dst = (e < N_EDGES) ? ei[N_EDGES + e] : e - N_EDGES;
    atomicAdd(&deg_i[dst], 1);
}

__global__ void scan1(const int* __restrict__ in, int* __restrict__ out, int* __restrict__ bsum, int n)
{
    __shared__ int s[256];
    int t = threadIdx.x, i = blockIdx.x * 256 + t;
    int v = (i < n) ? in[i] : 0;
    s[t] = v; __syncthreads();
    for (int off = 1; off < 256; off <<= 1) {
        int u = (t >= off) ? s[t - off] : 0;
        __syncthreads(); s[t] += u; __syncthreads();
    }
    if (i < n) out[i] = s[t] - v;
    if (t == 255) bsum[blockIdx.x] = s[255];
}

__global__ void scan2(int* __restrict__ bsum, int* __restrict__ total, int nb)
{
    if (threadIdx.x == 0 && blockIdx.x == 0) {
        int run = 0;
        for (int b = 0; b < nb; b++) { int t = bsum[b]; bsum[b] = run; run += t; }
        *total = run;
    }
}

__global__ void scan3(int* __restrict__ rs, const int* __restrict__ bsum, int n)
{
    int i = blockIdx.x * 256 + threadIdx.x;
    if (i < n) rs[i] += bsum[i >> 8];
}

__global__ void scatter_csr(const int* __restrict__ ei, const int* __restrict__ rs,
                            int* __restrict__ cursor, int* __restrict__ csr_src)
{
    int e = blockIdx.x * 256 + threadIdx.x;
    if (e >= N_ETOT) return;
    int src, dst;
    if (e < N_EDGES) { src = ei[e]; dst = ei[N_EDGES + e]; }
    else             { src = dst = e - N_EDGES; }
    int ofs = atomicAdd(&cursor[dst], 1);
    csr_src[rs[dst] + ofs] = src;
}

__global__ void gbounds(const int* __restrict__ batch, int* __restrict__ gb)
{
    int g = blockIdx.x * 256 + threadIdx.x;
    if (g > NG) return;
    int lo = 0, hi = N_NODES;
    while (lo < hi) { int mid = (lo + hi) >> 1; if (batch[mid] < g) lo = mid + 1; else hi = mid; }
    gb[g] = lo;
}

__global__ void dinv_k(const int* __restrict__ rs, float* __restrict__ dinv, int n)
{
    int i = blockIdx.x * 256 + threadIdx.x;
    if (i < n) dinv[i] = rsqrtf((float)(rs[i + 1] - rs[i]));
}

// ---------------- GAT ----------------
__global__ void att_scores(const float* __restrict__ x, const float* __restrict__ Asv,
                           const float* __restrict__ Adv, float* as_o, float* ad_o, int N)
{
    int n = blockIdx.x * 256 + threadIdx.x;
    if (n >= N) return;
    float xr[FXD];
#pragma unroll
    for (int k = 0; k < FXD; k++) xr[k] = x[n * FXD + k];
#pragma unroll
    for (int hd = 0; hd < HEADS; hd++) {
        float s = 0.f, d = 0.f;
#pragma unroll
        for (int k = 0; k < FXD; k++) {
            s = fmaf(xr[k], Asv[hd * FXD + k], s);
            d = fmaf(xr[k], Adv[hd * FXD + k], d);
        }
        as_o[n * HEADS + hd] = s;
        ad_o[n * HEADS + hd] = d;
    }
}

template<typename ST>
__global__ __launch_bounds__(256) void gat_fused(
    const int* __restrict__ rs, const int* __restrict__ csrc,
    const float* __restrict__ as_, const float* __restrict__ ad_,
    const float* __restrict__ x, ST* __restrict__ xagg)
{
    int wid = (blockIdx.x * 256 + threadIdx.x) >> 6;
    int lane = threadIdx.x & 63;
    if (wid >= N_NODES) return;
    int p0 = rs[wid], p1 = rs[wid + 1];
    float m = -1e30f, z = 0.f, ad = 0.f, zinv = 0.f;
    if (lane < HEADS) {
        ad = ad_[wid * HEADS + lane];
        for (int pos = p0; pos < p1; ++pos) {
            float v = as_[csrc[pos] * HEADS + lane] + ad;
            v = v >= 0.f ? v : 0.2f * v;
            m = fmaxf(m, v);
        }
        for (int pos = p0; pos < p1; ++pos) {
            float v = as_[csrc[pos] * HEADS + lane] + ad;
            v = v >= 0.f ? v : 0.2f * v;
            z += __expf(v - m);
        }
        zinv = 1.f / z;
    }
    int hdj[13], kj[13];
#pragma unroll
    for (int j = 0; j < 13; j++) {
        int f = lane + 64 * j;
        hdj[j] = (f < HDIM) ? f / FXD : 0;
        kj[j]  = (f < HDIM) ? f % FXD : 0;
    }
    float acc[13];
#pragma unroll
    for (int j = 0; j < 13; j++) acc[j] = 0.f;
    for (int pos = p0; pos < p1; ++pos) {
        int src = csrc[pos];
        float sc = 0.f;
        if (lane < HEADS) {
            float v = as_[src * HEADS + lane] + ad;
            v = v >= 0.f ? v : 0.2f * v;
            sc = __expf(v - m) * zinv;
        }
        const float* xs = x + (size_t)src * FXD;
#pragma unroll
        for (int j = 0; j < 13; j++) {
            float a = __shfl(sc, hdj[j]);
            int f = lane + 64 * j;
            if (f < HDIM) acc[j] = fmaf(a, xs[kj[j]], acc[j]);
        }
    }
    ST* od = xagg + (size_t)wid * HDIM;
#pragma unroll
    for (int j = 0; j < 13; j++) {
        int f = lane + 64 * j;
        if (f < HDIM) stv(&od[f], acc[j]);
    }
}

template<typename ST>
__global__ __launch_bounds__(256) void gat_headgemm(
    ST* __restrict__ h, const float* __restrict__ W, const float* __restrict__ bias)
{
    __shared__ float As[64][80];
    __shared__ float Bs[FXD][80];
    const int bm0 = blockIdx.x * 64;
    const int hd = blockIdx.y;
    const int tid = threadIdx.x;
    for (int idx = tid; idx < FXD * FXD; idx += 256) {
        int k = idx / FXD, f = idx % FXD;
        Bs[k][f] = W[k * HDIM + hd * FXD + f];
    }
    for (int idx = tid; idx < 64 * FXD; idx += 256) {
        int rl = idx / FXD, c = idx % FXD;
        int r = bm0 + rl;
        As[rl][c] = (r < N_NODES) ? ldv(&h[(size_t)r * HDIM + hd * FXD + c]) : 0.f;
    }
    __syncthreads();
    const int rl = tid >> 2, cg = tid & 3;
    float acc[20];
#pragma unroll
    for (int j = 0; j < 20; j++) acc[j] = 0.f;
    for (int k = 0; k < FXD; k++) {
        float a = As[rl][k];
#pragma unroll
        for (int j = 0; j < 20; j++) {
            int c = cg + 4 * j;
            if (c < FXD) acc[j] = fmaf(a, Bs[k][c], acc[j]);
        }
    }
    int r = bm0 + rl;
    if (r < N_NODES) {
#pragma unroll
        for (int j = 0; j < 20; j++) {
            int c = cg + 4 * j;
            if (c < FXD)
                stv(&h[(size_t)r * HDIM + hd * FXD + c],
                    fmaxf(acc[j] + bias[hd * FXD + c], 0.f));
        }
    }
}

// ---------------- GCN chunked ----------------
template<typename ST>
__global__ __launch_bounds__(256) void gcn_agg_chunk(
    const int* __restrict__ rs, const int* __restrict__ csrc,
    const ST* __restrict__ h1, const float* __restrict__ dinv,
    const int* __restrict__ gb, int g0, int g1, bf16* __restrict__ cbuf)
{
    int wid = (blockIdx.x * 256 + threadIdx.x) >> 6;
    int lane = threadIdx.x & 63;
    int n0 = gb[g0];
    int M = gb[g1] - n0; if (M > CCAP) M = CCAP;
    if (wid >= M) return;
    int dst = n0 + wid;
    int p0 = rs[dst], p1 = rs[dst + 1];
    float dd = dinv[dst];
    float acc[13];
#pragma unroll
    for (int j = 0; j < 13; j++) acc[j] = 0.f;
    for (int pos = p0; pos < p1; ++pos) {
        int src = csrc[pos];
        float norm = dinv[src] * dd;
        const ST* hs = h1 + (size_t)src * HDIM;
#pragma unroll
        for (int j = 0; j < 13; j++) {
            int f = lane + 64 * j;
            if (f < HDIM) acc[j] = fmaf(ldv(&hs[f]), norm, acc[j]);
        }
    }
    bf16* od = cbuf + (size_t)wid * LDK;
#pragma unroll
    for (int j = 0; j < 13; j++) {
        int f = lane + 64 * j;
        if (f < HDIM)      stv(&od[f], acc[j]);
        else if (f < LDK)  stv(&od[f], 0.f);
    }
}

// MFMA GEMM [M x HDIM] @ WT^T + bias + relu, fused max/sum pooling into catg.
__global__ __launch_bounds__(256) void gemm_pool_mfma(
    const bf16* __restrict__ A, const bf16* __restrict__ WT, const float* __restrict__ bias,
    const int* __restrict__ batch, const int* __restrict__ gb, int g0, int g1,
    float* __restrict__ catg)
{
    __shared__ unsigned short As[128][40];
    __shared__ unsigned short Bs[64][40];
    const int n0 = gb[g0];
    int M = gb[g1] - n0; if (M > CCAP) M = CCAP;
    const int bm0 = blockIdx.y * 128;
    if (bm0 >= M) return;
    const int bn0 = blockIdx.x * 64;
    const int tid = threadIdx.x;
    const int lane = tid & 63, w = tid >> 6;
    const int wr = (w >> 1) * 64, wc = (w & 1) * 32;
    const int fr_i = lane & 15, fk = (lane >> 4) * 8;

    f32x4 acc[4][2];
#pragma unroll
    for (int i = 0; i < 4; i++)
#pragma unroll
        for (int j = 0; j < 2; j++) acc[i][j] = (f32x4)(0.f);

    const int a_row = tid >> 1, a_ks = (tid & 1) * 16;
    const int b_col = tid >> 2, b_ks = (tid & 3) * 8;
    const bool rok = (bm0 + a_row) < M;
    const unsigned short* ga =
        (const unsigned short*)A + (size_t)(bm0 + a_row) * LDK + a_ks;
    const int gc = bn0 + b_col;
    const unsigned short* gw = (const unsigned short*)WT + (size_t)gc * LDK + b_ks;
    const short8 zv = (short8)(0);

    for (int k0 = 0; k0 < LDK; k0 += 32) {
#pragma unroll
        for (int h = 0; h < 2; h++)
            *(short8*)&As[a_row][a_ks + h * 8] =
                rok ? *(const short8*)(ga + k0 + h * 8) : zv;
        *(short8*)&Bs[b_col][b_ks] =
            (gc < HDIM) ? *(const short8*)(gw + k0) : zv;
        __syncthreads();
        short8 af[4], bf[2];
#pragma unroll
        for (int fr = 0; fr < 4; fr++)
            af[fr] = *(const short8*)&As[wr + fr * 16 + fr_i][fk];
#pragma unroll
        for (int fc = 0; fc < 2; fc++)
            bf[fc] = *(const short8*)&Bs[wc + fc * 16 + fr_i][fk];
#pragma unroll
        for (int fr = 0; fr < 4; fr++)
#pragma unroll
            for (int fc = 0; fc < 2; fc++)
                acc[fr][fc] = __builtin_amdgcn_mfma_f32_16x16x32_bf16(
                    af[fr], bf[fc], acc[fr][fc], 0, 0, 0);
        __syncthreads();
    }

#pragma unroll
    for (int fr = 0; fr < 4; fr++) {
        int r0 = bm0 + wr + fr * 16 + (lane >> 4) * 4;
        int gg[4]; bool valid[4];
#pragma unroll
        for (int j = 0; j < 4; j++) {
            int lr = r0 + j;
            valid[j] = lr < M;
            gg[j] = valid[j] ? batch[n0 + lr] : -1;
        }
#pragma unroll
        for (int fc = 0; fc < 2; fc++) {
            int c = bn0 + wc + fc * 16 + fr_i;
            if (c >= HDIM) continue;
            float bc = bias[c];
            int gcur = -1; float vmax = 0.f, vsum = 0.f;
#pragma unroll
            for (int j = 0; j < 4; j++) {
                if (!valid[j]) break;
                float v = fmaxf(acc[fr][fc][j] + bc, 0.f);
                if (gg[j] != gcur) {
                    if (gcur >= 0) {
                        atomicMax((int*)&catg[(size_t)gcur * (2 * HDIM) + c], __float_as_int(vmax));
                        atomicAdd(&catg[(size_t)gcur * (2 * HDIM) + HDIM + c], vsum);
                    }
                    gcur = gg[j]; vmax = v; vsum = v;
                } else { vmax = fmaxf(vmax, v); vsum += v; }
            }
            if (gcur >= 0) {
                atomicMax((int*)&catg[(size_t)gcur * (2 * HDIM) + c], __float_as_int(vmax));
                atomicAdd(&catg[(size_t)gcur * (2 * HDIM) + HDIM + c], vsum);
            }
        }
    }
}

__global__ void pool_div(float* __restrict__ catg, const int* __restrict__ gb)
{
    int i = blockIdx.x * 256 + threadIdx.x;
    if (i >= NG * HDIM) return;
    int g = i / HDIM, c = i - g * HDIM;
    float cnt = (float)(gb[g + 1] - gb[g]);
    catg[(size_t)g * (2 * HDIM) + HDIM + c] /= fmaxf(cnt, 1.f);
}

// ---------------- protein branch ----------------
__global__ void embed_k(const int* __restrict__ tgt, const float* __restrict__ emb,
                        bf16* __restrict__ xt)
{
    int row = blockIdx.x * 2 + (threadIdx.x >> 7);
    int c = threadIdx.x & 127;
    if (row >= NG * SEQ) return;
    int idx = tgt[row];
    stv(&xt[(size_t)row * 128 + c], emb[idx * 128 + c]);
}

// implicit-GEMM MFMA conv1d (K=16*CI), BN+relu fused; POOL -> global max into xp.
// block: one batch, 64 output t (4 waves x 16 rows), all CO.
template<int CI, int CO, bool POOL>
__global__ __launch_bounds__(256) void conv_mfma(
    const bf16* __restrict__ in, const bf16* __restrict__ wtc,
    const float* __restrict__ scale, const float* __restrict__ shift,
    bf16* __restrict__ out, int* __restrict__ xp, int Tin, int Tout)
{
    constexpr int K2 = 16 * CI;
    constexpr int KSTEPS = K2 / 32;
    constexpr int NCT = CO / 16;
    constexpr int ROWS = 79;
    constexpr int XM = (CI == 32) ? 3 : 7;      // XOR mask bits for row swizzle
    __shared__ __align__(16) bf16 in_s[ROWS * CI];
    __shared__ __align__(16) bf16 bw_s[2][CO * 32];
    __shared__ int smax[CO];
    const int b = blockIdx.x;
    const int t0 = blockIdx.y * 64;
    const int tid = threadIdx.x;
    const int lane = tid & 63, w = tid >> 6;
    const int fr_i = lane & 15;      // A row-in-tile / B,C col
    const int oct = lane >> 4;       // k-octet (0..3)

    if (POOL) for (int i = tid; i < CO; i += 256) smax[i] = 0;

    // stage input tile (XOR-swizzled 16B slots within each row)
    {
        const bf16* inb = in + (size_t)b * Tin * CI;
        constexpr int CPR = CI / 4;  // 8B chunks per row
        for (int c = tid; c < ROWS * CPR; c += 256) {
            int r = c / CPR, p = c % CPR;
            int t = t0 + r;
            unsigned long long v = 0;
            if (t < Tin) v = *(const unsigned long long*)(inb + (size_t)t * CI + p * 4);
            int byte = (p * 8) ^ ((r & XM) << 4);
            *(unsigned long long*)((char*)in_s + r * (CI * 2) + byte) = v;
        }
    }
    auto stageB = [&](int s, int buf) {
        for (int c = tid; c < CO * 8; c += 256) {
            int co = c >> 3, p = c & 7;
            unsigned long long v =
                *(const unsigned long long*)(wtc + (size_t)co * K2 + s * 32 + p * 4);
            int byte = (p * 8) ^ ((co & 3) << 4);
            *(unsigned long long*)((char*)&bw_s[buf][0] + co * 64 + byte) = v;
        }
    };
    stageB(0, 0);
    __syncthreads();

    f32x4 acc[NCT];
#pragma unroll
    for (int i = 0; i < NCT; i++) acc[i] = (f32x4)(0.f);

    for (int s = 0; s < KSTEPS; s++) {
        if (s + 1 < KSTEPS) stageB(s + 1, (s + 1) & 1);
        constexpr int SPK = CI / 32;             // K-steps per tap
        int kk = s / SPK;
        int ci0 = (s % SPK) * 32;
        int ar = w * 16 + fr_i + kk;             // input row for this lane
        int abyte = (ci0 * 2 + oct * 16) ^ ((ar & XM) << 4);
        short8 af = *(const short8*)((const char*)in_s + ar * (CI * 2) + abyte);
        const char* bwp = (const char*)&bw_s[s & 1][0];
#pragma unroll
        for (int fc = 0; fc < NCT; fc++) {
            int bco = fc * 16 + fr_i;
            int bbyte = (oct * 16) ^ ((bco & 3) << 4);
            short8 bf_ = *(const short8*)(bwp + bco * 64 + bbyte);
            acc[fc] = __builtin_amdgcn_mfma_f32_16x16x32_bf16(af, bf_, acc[fc], 0, 0, 0);
        }
        __syncthreads();
    }

    // epilogue: C col = fr_i, row = oct*4 + j
    int tb = t0 + w * 16 + oct * 4;
#pragma unroll
    for (int fc = 0; fc < NCT; fc++) {
        int co = fc * 16 + fr_i;
        float sc_ = scale[co], sh_ = shift[co];
        if (POOL) {
            float vm = 0.f; bool any = false;
#pragma unroll
            for (int j = 0; j < 4; j++) {
                if (tb + j < Tout) {
                    float v = fmaxf(fmaf(acc[fc][j], sc_, sh_), 0.f);
                    vm = fmaxf(vm, v); any = true;
                }
            }
            if (any) atomicMax(&smax[co], __float_as_int(vm));
        } else {
#pragma unroll
            for (int j = 0; j < 4; j++) {
                int t = tb + j;
                if (t < Tout) {
                    float v = fmaxf(fmaf(acc[fc][j], sc_, sh_), 0.f);
                    out[((size_t)b * Tout + t) * CO + co] = __float2bfloat16(v);
                }
            }
        }
    }
    if (POOL) {
        __syncthreads();
        for (int i = tid; i < CO; i += 256)
            atomicMax(&xp[b * CO + i], smax[i]);
    }
}

// ---------------- head final ----------------
__global__ void out_layer(const float* __restrict__ f2, const float* __restrict__ w,
                          const float* __restrict__ b, float* __restrict__ out)
{
    int r = (blockIdx.x * 256 + threadIdx.x) >> 6;
    int lane = threadIdx.x & 63;
    if (r >= NG) return;
    float s = 0.f;
    for (int k = lane; k < 512; k += 64) s = fmaf(f2[r * 512 + k], w[k], s);
#pragma unroll
    for (int off = 32; off >= 1; off >>= 1) s += __shfl_down(s, off);
    if (lane == 0) out[r] = s + b[0];
}

// ---------------- pipeline ----------------
template<typename ST>
static void run_pipeline(void* const* d_in, float* d_out, char* ws, hipStream_t stream)
{
    const float* x      = (const float*)d_in[0];
    const int*   ei     = (const int*)d_in[1];
    const int*   batch  = (const int*)d_in[2];
    const int*   target = (const int*)d_in[3];
    const float* gat_w  = (const float*)d_in[4];
    const float* gat_as = (const float*)d_in[5];
    const float* gat_ad = (const float*)d_in[6];
    const float* gat_b  = (const float*)d_in[7];
    const float* gcn_w  = (const float*)d_in[8];
    const float* gcn_b  = (const float*)d_in[9];
    const float* fcg1_w = (const float*)d_in[10];
    const float* fcg1_b = (const float*)d_in[11];
    const float* fcg2_w = (const float*)d_in[12];
    const float* fcg2_b = (const float*)d_in[13];
    const float* emb    = (const float*)d_in[14];
    const float* c1_w   = (const float*)d_in[15];
    const float* c1_b   = (const float*)d_in[16];
    const float* bn1_g  = (const float*)d_in[17];
    const float* bn1_b  = (const float*)d_in[18];
    const float* bn1_m  = (const float*)d_in[19];
    const float* bn1_v  = (const float*)d_in[20];
    const float* c2_w   = (const float*)d_in[21];
    const float* c2_b   = (const float*)d_in[22];
    const float* bn2_g  = (const float*)d_in[23];
    const float* bn2_b  = (const float*)d_in[24];
    const float* bn2_m  = (const float*)d_in[25];
    const float* bn2_v  = (const float*)d_in[26];
    const float* c3_w   = (const float*)d_in[27];
    const float* c3_b   = (const float*)d_in[28];
    const float* bn3_g  = (const float*)d_in[29];
    const float* bn3_b  = (const float*)d_in[30];
    const float* bn3_m  = (const float*)d_in[31];
    const float* bn3_v  = (const float*)d_in[32];
    const float* fcxt_w = (const float*)d_in[33];
    const float* fcxt_b = (const float*)d_in[34];
    const float* bnf_g  = (const float*)d_in[35];
    const float* bnf_b  = (const float*)d_in[36];
    const float* bnf_m  = (const float*)d_in[37];
    const float* bnf_v  = (const float*)d_in[38];
    const float* fc1_w  = (const float*)d_in[39];
    const float* fc1_b  = (const float*)d_in[40];
    const float* fc2_w  = (const float*)d_in[41];
    const float* fc2_b  = (const float*)d_in[42];
    const float* out_w  = (const float*)d_in[43];
    const float* out_b  = (const float*)d_in[44];

    size_t off = 0;
    auto alloc = [&](size_t bytes) -> void* {
        void* p = ws + off;
        off = (off + bytes + 255) & ~(size_t)255;
        return p;
    };
    ST*    bufA  = (ST*)alloc((size_t)N_NODES * HDIM * sizeof(ST));
    bf16*  cbuf  = (bf16*)alloc((size_t)CCAP * LDK * sizeof(bf16));
    bf16*  WT    = (bf16*)alloc((size_t)HDIM * LDK * sizeof(bf16));
    bf16*  wt1c  = (bf16*)alloc((size_t)32 * 2048 * 2);
    bf16*  wt2c  = (bf16*)alloc((size_t)64 * 512 * 2);
    bf16*  wt3c  = (bf16*)alloc((size_t)96 * 1024 * 2);
    float* a_s   = (float*)alloc((size_t)N_NODES * HEADS * 4);
    float* a_d   = (float*)alloc((size_t)N_NODES * HEADS * 4);
    int*   deg_i = (int*)alloc((size_t)N_NODES * 4);
    int*   rs    = (int*)alloc((size_t)(N_NODES + 1) * 4);
    int*   cursor= (int*)alloc((size_t)N_NODES * 4);
    int*   csrc  = (int*)alloc((size_t)N_ETOT * 4);
    int*   bsum  = (int*)alloc(512 * 4);
    int*   gb    = (int*)alloc((NG + 1) * 4);
    float* dinv  = (float*)alloc((size_t)N_NODES * 4);
    float* catg  = (float*)alloc((size_t)NG * 2 * HDIM * 4);
    float* g1    = (float*)alloc((size_t)NG * 1500 * 4);
    float* catH  = (float*)alloc((size_t)NG * 256 * 4);
    float* f1    = (float*)alloc((size_t)NG * 1024 * 4);
    float* f2    = (float*)alloc((size_t)NG * 512 * 4);
    int*   xp    = (int*)alloc((size_t)NG * 96 * 4);
    float* Asv   = (float*)alloc((size_t)HEADS * FXD * 4);
    float* Adv   = (float*)alloc((size_t)HEADS * FXD * 4);
    float* sc1 = (float*)alloc(32*4);  float* sh1 = (float*)alloc(32*4);
    float* sc2 = (float*)alloc(64*4);  float* sh2 = (float*)alloc(64*4);
    float* sc3 = (float*)alloc(96*4);  float* sh3 = (float*)alloc(96*4);
    float* scf = (float*)alloc(128*4); float* shf = (float*)alloc(128*4);

    const int NB = (N_NODES + 255) / 256;

    zero32<<<NB, 256, 0, stream>>>(deg_i, N_NODES);
    zero32<<<NB, 256, 0, stream>>>(cursor, N_NODES);
    zero32<<<(NG * 2 * HDIM + 255) / 256, 256, 0, stream>>>((int*)catg, NG * 2 * HDIM);
    zero32<<<(NG * 96 + 255) / 256, 256, 0, stream>>>(xp, NG * 96);

    prep_att<<<4, 256, 0, stream>>>(gat_w, gat_as, gat_ad, Asv, Adv);
    wt_k<<<(HDIM * LDK + 255) / 256, 256, 0, stream>>>(gcn_w, WT);
    prep_wt_conv<128, 32><<<256, 256, 0, stream>>>(c1_w, wt1c);
    prep_wt_conv<32, 64><<<128, 256, 0, stream>>>(c2_w, wt2c);
    prep_wt_conv<64, 96><<<384, 256, 0, stream>>>(c3_w, wt3c);
    prep_bn<<<1, 256, 0, stream>>>(c1_b, bn1_g, bn1_b, bn1_m, bn1_v, sc1, sh1, 32, 0);
    prep_bn<<<1, 256, 0, stream>>>(c2_b, bn2_g, bn2_b, bn2_m, bn2_v, sc2, sh2, 64, 0);
    prep_bn<<<1, 256, 0, stream>>>(c3_b, bn3_g, bn3_b, bn3_m, bn3_v, sc3, sh3, 96, 0);
    prep_bn<<<1, 256, 0, stream>>>(fcxt_b, bnf_g, bnf_b, bnf_m, bnf_v, scf, shf, 128, 1);

    hist_deg<<<(N_ETOT + 255) / 256, 256, 0, stream>>>(ei, deg_i);
    scan1<<<NB, 256, 0, stream>>>(deg_i, rs, bsum, N_NODES);
    scan2<<<1, 64, 0, stream>>>(bsum, rs + N_NODES, NB);
    scan3<<<NB, 256, 0, stream>>>(rs, bsum, N_NODES);
    scatter_csr<<<(N_ETOT + 255) / 256, 256, 0, stream>>>(ei, rs, cursor, csrc);
    gbounds<<<3, 256, 0, stream>>>(batch, gb);
    dinv_k<<<NB, 256, 0, stream>>>(rs, dinv, N_NODES);

    // GAT
    att_scores<<<NB, 256, 0, stream>>>(x, Asv, Adv, a_s, a_d, N_NODES);
    gat_fused<ST><<<(N_NODES * 64) / 256, 256, 0, stream>>>(rs, csrc, a_s, a_d, x, bufA);
    gat_headgemm<ST><<<dim3((N_NODES + 63) / 64, HEADS), 256, 0, stream>>>(bufA, gat_w, gat_b);

    // GCN chunked: aggregate -> MFMA GEMM + fused pooling
    for (int c = 0; c < NCHUNK; c++) {
        gcn_agg_chunk<ST><<<(CCAP * 64) / 256, 256, 0, stream>>>(
            rs, csrc, bufA, dinv, gb, c * GPC, (c + 1) * GPC, cbuf);
        gemm_pool_mfma<<<dim3(13, CCAP / 128), 256, 0, stream>>>(
            cbuf, WT, gcn_b, batch, gb, c * GPC, (c + 1) * GPC, catg);
    }
    pool_div<<<(NG * HDIM + 255) / 256, 256, 0, stream>>>(catg, gb);

    gemm_t<true, false, true><<<dim3(4, 24), 256, 0, stream>>>(
        catg, fcg1_w, fcg1_b, nullptr, nullptr, g1, NG, 1500, 2 * HDIM, 2 * HDIM, 1500, 1500);
    gemm_t<true, false, false><<<dim3(4, 2), 256, 0, stream>>>(
        g1, fcg2_w, fcg2_b, nullptr, nullptr, catH, NG, 128, 1500, 1500, 128, 256);

    // protein branch: embed -> 3x MFMA conv (BN+relu fused; conv3 + maxpool fused)
    bf16* pbufA = (bf16*)bufA;
    embed_k<<<NG * SEQ / 2, 256, 0, stream>>>(target, emb, pbufA);
    conv_mfma<128, 32, false><<<dim3(NG, 16), 256, 0, stream>>>(pbufA, wt1c, sc1, sh1, cbuf, nullptr, 1000, 985);
    conv_mfma<32, 64, false><<<dim3(NG, 16), 256, 0, stream>>>(cbuf, wt2c, sc2, sh2, pbufA, nullptr, 985, 970);
    conv_mfma<64, 96, true><<<dim3(NG, 15), 256, 0, stream>>>(pbufA, wt3c, sc3, sh3, (bf16*)nullptr, xp, 970, 955);
    gemm_t<true, true, true><<<dim3(4, 2), 256, 0, stream>>>(
        (const float*)xp, fcxt_w, fcxt_b, scf, shf, catH + 128, NG, 128, 96, 96, 128, 256);

    gemm_t<true, false, true><<<dim3(4, 16), 256, 0, stream>>>(
        catH, fc1_w, fc1_b, nullptr, nullptr, f1, NG, 1024, 256, 256, 1024, 1024);
    gemm_t<true, false, true><<<dim3(4, 8), 256, 0, stream>>>(
        f1, fc2_w, fc2_b, nullptr, nullptr, f2, NG, 512, 1024, 1024, 512, 512);
    out_layer<<<128, 256, 0, stream>>>(f2, out_w, out_b, d_out);
}

static size_t footprint(size_t esz)
{
    auto al = [](size_t b) { return (b + 255) & ~(size_t)255; };
    size_t s = 0;
    s += al((size_t)N_NODES * HDIM * esz);
    s += al((size_t)CCAP * LDK * 2);
    s += al((size_t)HDIM * LDK * 2);
    s += al((size_t)32 * 2048 * 2) + al((size_t)64 * 512 * 2) + al((size_t)96 * 1024 * 2);
    s += al((size_t)N_NODES * HEADS * 4) * 2;
    s += al((size_t)N_NODES * 4) * 3 + al((size_t)(N_NODES + 1) * 4);
    s += al((size_t)N_ETOT * 4);
    s += al(512 * 4) + al((NG + 1) * 4);
    s += al((size_t)NG * 2 * HDIM * 4);
    s += al((size_t)NG * 1500 * 4) + al((size_t)NG * 256 * 4) + al((size_t)NG * 1024 * 4)
       + al((size_t)NG * 512 * 4) + al((size_t)NG * 96 * 4);
    s += al(HEADS * FXD * 4) * 2 + 16 * 1024;
    return s + (16ull << 20);
}

extern "C" void kernel_launch(void* const* d_in, const int* in_sizes, int n_in,
                              void* d_out, int out_size, void* d_ws, size_t ws_size,
                              hipStream_t stream)
{
    if (ws_size >= footprint(sizeof(float)))
        run_pipeline<float>(d_in, (float*)d_out, (char*)d_ws, stream);
    else
        run_pipeline<bf16>(d_in, (float*)d_out, (char*)d_ws, stream);
}